// Round 4
// baseline (543.348 us; speedup 1.0000x reference)
//
#include <hip/hip_runtime.h>
#include <math.h>

#define HH 128
#define WW 128
#define CC 64

typedef __attribute__((ext_vector_type(8))) short s16x8;
typedef __attribute__((ext_vector_type(4))) float f32x4;

__device__ __forceinline__ float gelu_f(float x){
    return 0.5f * x * (1.0f + erff(x * 0.70710678118654752440f));
}
// tanh-approx gelu: max abs err ~4e-4, uses v_exp_f32 + v_rcp
__device__ __forceinline__ float gelu_fast(float x){
    const float u2 = 1.5957691216057308f * x * (1.0f + 0.044715f * x * x); // 2*a*(x+bx^3)
    const float e  = __expf(u2);
    const float t  = 1.0f - 2.0f / (e + 1.0f);
    return 0.5f * x * (1.0f + t);
}
__device__ __forceinline__ int refl(int v, int n){
    return v < 0 ? -v : (v >= n ? 2*n - 2 - v : v);
}
__device__ __forceinline__ ushort f2bf(float f){
    unsigned int b = __float_as_uint(f);
    unsigned int r = (b + 0x7FFFu + ((b >> 16) & 1u)) >> 16;
    return (ushort)r;
}

// ---------------------------------------------------------------------------
// featT_kernel: featT[b][row][col][c] = bf16(feat[b][c][row][col])
// ---------------------------------------------------------------------------
__global__ __launch_bounds__(256) void featT_kernel(
    const float* __restrict__ feat, ushort* __restrict__ featT)
{
    const int i = blockIdx.x * 256 + threadIdx.x;   // 0..262143
    const int col = i & 127;
    const int cb  = (i >> 7) & 7;
    const int row = (i >> 10) & 127;
    const int b   = (i >> 17) & 1;

    const float* __restrict__ src = feat + ((size_t)(b*64 + cb*8) << 14) + (row << 7) + col;
    ushort tmp[8];
    #pragma unroll
    for (int j = 0; j < 8; ++j) tmp[j] = f2bf(src[(size_t)j << 14]);
    ushort* dst = featT + ((((size_t)(b*128 + row) << 7) + col) << 6) + cb*8;
    *(int4*)dst = *(const int4*)tmp;
}

// ---------------------------------------------------------------------------
// prep_wtap: wk1tap[tap][o][c] = bf16(wk1[o][c*9+tap]).  9*128*64
// ---------------------------------------------------------------------------
__global__ __launch_bounds__(256) void prep_wtap(
    const float* __restrict__ wk1, ushort* __restrict__ wk1tap)
{
    const int i = blockIdx.x * 256 + threadIdx.x;   // 0..73727
    if (i >= 73728) return;
    const int c   = i & 63;
    const int o   = (i >> 6) & 127;
    const int tap = i >> 13;
    wk1tap[i] = f2bf(wk1[o*640 + c*9 + tap]);
}

// ---------------------------------------------------------------------------
// prep_kernel: contrib[p][o] (4x128) and wk2p[o][12] packed transpose
// ---------------------------------------------------------------------------
__global__ __launch_bounds__(256) void prep_kernel(
    const float* __restrict__ w1m, const float* __restrict__ b1m,
    const float* __restrict__ w2m, const float* __restrict__ b2m,
    const float* __restrict__ wk1, const float* __restrict__ bk1,
    const float* __restrict__ wk2,
    float* __restrict__ contrib, float* __restrict__ wk2p)
{
    __shared__ float m_emb[4][64];
    const int t = threadIdx.x;
    const int p = t >> 6;
    const int o = t & 63;

    const float du = (p & 1) ? -0.25f : 0.25f;
    const float dv = (p >> 1) ? -0.25f : 0.25f;
    const float mv[5] = {2.0f, du, dv, 0.5f, 0.3f};

    float enc[85];
    #pragma unroll
    for (int f = 0; f < 5; ++f){
        enc[f*17] = mv[f];
        float fr = 3.14159265358979323846f;
        #pragma unroll
        for (int b = 0; b < 8; ++b){
            float xb = mv[f] * fr;
            enc[f*17 + 1 + b] = sinf(xb);
            enc[f*17 + 9 + b] = cosf(xb);
            fr *= 2.0f;
        }
    }

    float acc = b2m[o];
    for (int j = 0; j < 64; ++j){
        float h = b1m[j];
        #pragma unroll
        for (int i = 0; i < 85; ++i) h += enc[i] * w1m[j*85 + i];
        acc += gelu_f(h) * w2m[o*64 + j];
    }
    m_emb[p][o] = acc;
    __syncthreads();

    for (int e = t; e < 512; e += 256){
        const int pp = e >> 7;
        const int oo = e & 127;
        float a = bk1[oo];
        #pragma unroll
        for (int j = 0; j < 64; ++j) a += m_emb[pp][j] * wk1[oo*640 + 576 + j];
        contrib[e] = a;
    }
    for (int e = t; e < 1536; e += 256){
        const int oo = e / 12;
        const int kk = e % 12;
        wk2p[e] = (kk < 9) ? wk2[kk*128 + oo] : 0.0f;
    }
}

// ---------------------------------------------------------------------------
// conv_kernel: implicit-GEMM 3x3 conv. L[b][cell][o] = patch . wk1 (pre-bias)
// Block: 512 threads / 8 waves; tile 64 cells (2 rows x 32 cx) x 128 o.
// ---------------------------------------------------------------------------
__global__ __launch_bounds__(512) void conv_kernel(
    const ushort* __restrict__ featT,
    const ushort* __restrict__ wk1tap,
    float* __restrict__ L)
{
    __shared__ ushort As[4*34*64];   // [row][col][c] with c-block XOR swizzle

    const int t   = threadIdx.x;
    const int blk = blockIdx.x;
    const int b   = blk >> 8;
    const int rem = blk & 255;
    const int cy0 = (rem >> 2) * 2;
    const int cx0 = (rem & 3) * 32;

    // ---- stage A: rows cy0-1..cy0+2 (refl), cols cx0-1..cx0+32 (refl) ----
    for (int e = t; e < 1088; e += 512){
        const int r   = e / 272;
        const int rm  = e - r * 272;
        const int col = rm >> 3;
        const int cb  = rm & 7;
        const int grow = refl(cy0 - 1 + r, HH);
        const int gcol = refl(cx0 - 1 + col, WW);
        const ushort* src = featT + ((((size_t)(b*128 + grow) << 7) + gcol) << 6) + cb*8;
        const int didx = (r*34 + col)*64 + ((cb ^ (col & 7)) << 3);
        *(int4*)&As[didx] = *(const int4*)src;
    }
    __syncthreads();

    const int lane = t & 63;
    const int w    = t >> 6;
    const int wn   = w & 1;          // o half (64 each)
    const int wq   = w >> 1;
    const int cellrow = wq >> 1;     // 0/1
    const int colblk  = (wq & 1) * 16;
    const int l15  = lane & 15;
    const int l4   = lane >> 4;

    f32x4 acc[4];
    #pragma unroll
    for (int n = 0; n < 4; ++n) acc[n] = (f32x4){0.f,0.f,0.f,0.f};

    const int acol = colblk + l15;   // + kx below

    #pragma unroll
    for (int tap = 0; tap < 9; ++tap){
        const int ky = tap / 3;
        const int kx = tap - ky * 3;

        // B fragments (global, L2-hot): 2 ks x 4 n
        s16x8 bf[2][4];
        #pragma unroll
        for (int ks = 0; ks < 2; ++ks)
            #pragma unroll
            for (int n = 0; n < 4; ++n)
                bf[ks][n] = *(const s16x8*)(wk1tap +
                    (((size_t)tap << 13) + ((wn*64 + n*16 + l15) << 6) + ks*32 + l4*8));

        const int col = acol + kx;
        const int rowbase = (cellrow + ky)*34 + col;
        const int sw = (col & 7);
        #pragma unroll
        for (int ks = 0; ks < 2; ++ks){
            const int cb0 = ks*4 + l4;
            const s16x8 af = *(const s16x8*)&As[rowbase*64 + (((cb0) ^ sw) << 3)];
            #pragma unroll
            for (int n = 0; n < 4; ++n)
                acc[n] = __builtin_amdgcn_mfma_f32_16x16x32_bf16(af, bf[ks][n], acc[n], 0, 0, 0);
        }
    }

    // ---- epilogue: D col=o (l15), row=cell (l4*4+reg) ----
    #pragma unroll
    for (int n = 0; n < 4; ++n){
        #pragma unroll
        for (int reg = 0; reg < 4; ++reg){
            const int cellg = (cy0 + cellrow)*128 + cx0 + colblk + l4*4 + reg;
            const int o = wn*64 + n*16 + l15;
            L[(((size_t)b*16384 + cellg) << 7) + o] = acc[n][reg];
        }
    }
}

// ---------------------------------------------------------------------------
// tail_kernel: 2 threads per pixel (half = tid&1). 1024 blocks x 256.
// ALL shuffles execute under full convergence (outside any half-branch).
// ---------------------------------------------------------------------------
__global__ __launch_bounds__(256, 4) void tail_kernel(
    const float* __restrict__ feat,
    const float* __restrict__ L,
    const float* __restrict__ contrib,
    const float* __restrict__ wk2p, const float* __restrict__ bk2,
    const float* __restrict__ wr1, const float* __restrict__ br1,
    const float* __restrict__ wr2, const float* __restrict__ br2,
    float* __restrict__ out)
{
    __shared__ float cl_s[512];
    __shared__ float wk2s[1536];
    __shared__ float wr2s[192];
    for (int e = threadIdx.x; e < 512;  e += 256) cl_s[e] = contrib[e];
    for (int e = threadIdx.x; e < 1536; e += 256) wk2s[e] = wk2p[e];
    for (int e = threadIdx.x; e < 192;  e += 256) wr2s[e] = wr2[e];
    __syncthreads();

    const int tid   = blockIdx.x * 256 + threadIdx.x;
    const int half  = tid & 1;
    const int pixel = tid >> 1;
    const int b  = pixel >> 16;
    const int qi = pixel & 65535;
    const int oy = qi >> 8;
    const int ox = qi & 255;

    int cy = (oy - 1) >> 1; if (cy < 0) cy = 0;
    int cx = (ox - 1) >> 1; if (cx < 0) cx = 0;

    int ry[3], rx[3];
    #pragma unroll
    for (int k = 0; k < 3; ++k){
        ry[k] = refl(cy - 1 + k, HH);
        rx[k] = refl(cx - 1 + k, WW);
    }

    const int p = ((oy & 1) << 1) | (ox & 1);
    const float* __restrict__ fb = feat + ((size_t)b << 20);  // b*64*128*128
    const f32x4* __restrict__ myL =
        (const f32x4*)(L + (((size_t)b*16384 + cy*128 + cx) << 7)) + half*16;
    const float* __restrict__ clp = cl_s + p*128 + half*64;

    // ---- h (my 64 of 128) -> partial w9 ----
    float w9[9];
    #pragma unroll
    for (int k = 0; k < 9; ++k) w9[k] = 0.0f;

    #pragma unroll
    for (int i = 0; i < 16; ++i){
        const f32x4 lv = myL[i];
        #pragma unroll
        for (int j = 0; j < 4; ++j){
            const int oo = i*4 + j;
            const float h = gelu_fast(lv[j] + clp[oo]);
            const f32x4* wrow = (const f32x4*)&wk2s[(half*64 + oo)*12];
            const f32x4 w0 = wrow[0], w1 = wrow[1], w2v = wrow[2];
            w9[0] += h*w0[0]; w9[1] += h*w0[1]; w9[2] += h*w0[2]; w9[3] += h*w0[3];
            w9[4] += h*w1[0]; w9[5] += h*w1[1]; w9[6] += h*w1[2]; w9[7] += h*w1[3];
            w9[8] += h*w2v[0];
        }
    }
    // combine pair (uniform shfl) + bias
    #pragma unroll
    for (int k = 0; k < 9; ++k) w9[k] += __shfl_xor(w9[k], 1);
    #pragma unroll
    for (int k = 0; k < 9; ++k) w9[k] += bk2[k];

    // ---- softmax(9) ----
    float mx = w9[0];
    #pragma unroll
    for (int k = 1; k < 9; ++k) mx = fmaxf(mx, w9[k]);
    float sum = 0.0f;
    #pragma unroll
    for (int k = 0; k < 9; ++k){ w9[k] = __expf(w9[k] - mx); sum += w9[k]; }
    const float inv = 1.0f / sum;
    #pragma unroll
    for (int k = 0; k < 9; ++k) w9[k] *= inv;

    // ---- fq: channel-split partial sums. half h owns ch in [32h, 32h+32).
    //      fq_part[c] = sum over my channels' j=ch*9+kk of w9[j>>6]*v[kk],
    //      where c = j&63. Compile-time indices inside each arm; NO shfl here.
    float fq_part[64];
    #pragma unroll
    for (int c = 0; c < 64; ++c) fq_part[c] = 0.0f;

    if (half == 0){
        #pragma unroll
        for (int ch = 0; ch < 32; ++ch){
            const float* fc = fb + ch*16384;
            float v[9];
            #pragma unroll
            for (int kk = 0; kk < 9; ++kk) v[kk] = fc[ry[kk/3]*128 + rx[kk%3]];
            #pragma unroll
            for (int kk = 0; kk < 9; ++kk){
                const int j = ch*9 + kk;
                fq_part[j & 63] += w9[j >> 6] * v[kk];
            }
        }
    } else {
        #pragma unroll
        for (int ch = 32; ch < 64; ++ch){
            const float* fc = fb + ch*16384;
            float v[9];
            #pragma unroll
            for (int kk = 0; kk < 9; ++kk) v[kk] = fc[ry[kk/3]*128 + rx[kk%3]];
            #pragma unroll
            for (int kk = 0; kk < 9; ++kk){
                const int j = ch*9 + kk;
                fq_part[j & 63] += w9[j >> 6] * v[kk];
            }
        }
    }

    // ---- uniform combine: fq[c] = my partial + partner partial ----
    #pragma unroll
    for (int c = 0; c < 64; ++c)
        fq_part[c] += __shfl_xor(fq_part[c], 1);

    // ---- RGB MLP: my 32 of 64 hidden ----
    float r0 = 0.f, r1 = 0.f, r2 = 0.f;
    #pragma unroll
    for (int oi = 0; oi < 32; ++oi){
        const int o = half*32 + oi;
        const f32x4* w4 = (const f32x4*)(wr1 + (o << 6));
        float a = br1[o];
        #pragma unroll
        for (int ci = 0; ci < 16; ++ci){
            const f32x4 wv = w4[ci];
            a += fq_part[ci*4+0]*wv[0] + fq_part[ci*4+1]*wv[1]
               + fq_part[ci*4+2]*wv[2] + fq_part[ci*4+3]*wv[3];
        }
        const float h = gelu_fast(a);
        r0 += h * wr2s[o];
        r1 += h * wr2s[64 + o];
        r2 += h * wr2s[128 + o];
    }
    r0 += __shfl_xor(r0, 1);
    r1 += __shfl_xor(r1, 1);
    r2 += __shfl_xor(r2, 1);

    if (half == 0){
        const int pix = (oy << 8) | ox;
        out[((size_t)(b*3 + 0) << 16) + pix] = r0 + br2[0];
        out[((size_t)(b*3 + 1) << 16) + pix] = r1 + br2[1];
        out[((size_t)(b*3 + 2) << 16) + pix] = r2 + br2[2];
    }
}

// ---------------------------------------------------------------------------
// Fallback monolithic kernel (round-1; used only if ws too small)
// ---------------------------------------------------------------------------
__global__ __launch_bounds__(256) void main_kernel_mono(
    const float* __restrict__ feat,
    const float* __restrict__ wk1,
    const float* __restrict__ wk2, const float* __restrict__ bk2,
    const float* __restrict__ wr1, const float* __restrict__ br1,
    const float* __restrict__ wr2, const float* __restrict__ br2,
    const float* __restrict__ contrib,
    float* __restrict__ out)
{
    const int tid = blockIdx.x * 256 + threadIdx.x;
    const int b  = tid >> 16;
    const int qi = tid & 65535;
    const int oy = qi >> 8;
    const int ox = qi & 255;

    int cy = (oy - 1) >> 1; if (cy < 0) cy = 0;
    int cx = (ox - 1) >> 1; if (cx < 0) cx = 0;

    int ry[3], rx[3];
    #pragma unroll
    for (int k = 0; k < 3; ++k){ ry[k] = refl(cy-1+k, HH); rx[k] = refl(cx-1+k, WW); }

    const int p = ((oy & 1) << 1) | (ox & 1);
    const float* __restrict__ fb = feat + ((size_t)b << 20);

    float w9[9];
    #pragma unroll
    for (int k = 0; k < 9; ++k) w9[k] = bk2[k];

    for (int oc = 0; oc < 4; ++oc){
        float acc[32];
        #pragma unroll
        for (int j = 0; j < 32; ++j) acc[j] = contrib[p*128 + oc*32 + j];
        for (int c = 0; c < CC; ++c){
            const float* __restrict__ fc = fb + c * (HH*WW);
            float v[9];
            #pragma unroll
            for (int ky = 0; ky < 3; ++ky){
                const float* __restrict__ frow = fc + ry[ky] * WW;
                #pragma unroll
                for (int kx = 0; kx < 3; ++kx) v[ky*3 + kx] = frow[rx[kx]];
            }
            const float* __restrict__ wrow0 = wk1 + (oc*32) * 640 + c * 9;
            #pragma unroll
            for (int j = 0; j < 32; ++j){
                const float* __restrict__ wrow = wrow0 + j * 640;
                float a = acc[j];
                #pragma unroll
                for (int kk = 0; kk < 9; ++kk) a += v[kk] * wrow[kk];
                acc[j] = a;
            }
        }
        #pragma unroll
        for (int j = 0; j < 32; ++j){
            const float h = gelu_f(acc[j]);
            const int o = oc*32 + j;
            #pragma unroll
            for (int k = 0; k < 9; ++k) w9[k] += h * wk2[k*128 + o];
        }
    }

    float mx = w9[0];
    #pragma unroll
    for (int k = 1; k < 9; ++k) mx = fmaxf(mx, w9[k]);
    float sum = 0.0f;
    #pragma unroll
    for (int k = 0; k < 9; ++k){ w9[k] = expf(w9[k] - mx); sum += w9[k]; }
    const float inv = 1.0f / sum;
    #pragma unroll
    for (int k = 0; k < 9; ++k) w9[k] *= inv;

    float fq[64];
    #pragma unroll
    for (int c = 0; c < 64; ++c){
        float a = 0.0f;
        #pragma unroll
        for (int k = 0; k < 9; ++k){
            const int j  = k*64 + c;
            const int ch = j / 9;
            const int kk = j % 9;
            a += w9[k] * fb[ch*(HH*WW) + ry[kk/3]*WW + rx[kk%3]];
        }
        fq[c] = a;
    }

    float r0 = br2[0], r1 = br2[1], r2 = br2[2];
    for (int o = 0; o < 64; ++o){
        float a = br1[o];
        #pragma unroll
        for (int c = 0; c < 64; ++c) a += fq[c] * wr1[o*64 + c];
        const float h = gelu_f(a);
        r0 += h * wr2[o];
        r1 += h * wr2[64 + o];
        r2 += h * wr2[128 + o];
    }

    const int pix = (oy << 8) | ox;
    out[((size_t)(b*3 + 0) << 16) + pix] = r0;
    out[((size_t)(b*3 + 1) << 16) + pix] = r1;
    out[((size_t)(b*3 + 2) << 16) + pix] = r2;
}

extern "C" void kernel_launch(void* const* d_in, const int* in_sizes, int n_in,
                              void* d_out, int out_size, void* d_ws, size_t ws_size,
                              hipStream_t stream)
{
    const float* feat = (const float*)d_in[0];
    const float* w1m  = (const float*)d_in[1];
    const float* b1m  = (const float*)d_in[2];
    const float* w2m  = (const float*)d_in[3];
    const float* b2m  = (const float*)d_in[4];
    const float* wk1  = (const float*)d_in[5];
    const float* bk1  = (const float*)d_in[6];
    const float* wk2  = (const float*)d_in[7];
    const float* bk2  = (const float*)d_in[8];
    const float* wr1  = (const float*)d_in[9];
    const float* br1  = (const float*)d_in[10];
    const float* wr2  = (const float*)d_in[11];
    const float* br2  = (const float*)d_in[12];

    float* out = (float*)d_out;

    // ws layout
    char* ws = (char*)d_ws;
    float*  contrib = (float*)ws;                      // 512 f = 2048 B
    float*  wk2p    = (float*)(ws + 2048);             // 1536 f = 6144 B
    ushort* wk1tap  = (ushort*)(ws + 8192);            // 73728 us = 147456 B
    ushort* featT   = (ushort*)(ws + 155648);          // 2097152 us = 4194304 B
    float*  L       = (float*)(ws + 4349952);          // 4194304 f = 16777216 B
    const size_t need = 4349952 + 16777216;

    hipLaunchKernelGGL(prep_kernel, dim3(1), dim3(256), 0, stream,
                       w1m, b1m, w2m, b2m, wk1, bk1, wk2, contrib, wk2p);

    if (ws_size >= need){
        hipLaunchKernelGGL(featT_kernel, dim3(1024), dim3(256), 0, stream, feat, featT);
        hipLaunchKernelGGL(prep_wtap, dim3(288), dim3(256), 0, stream, wk1, wk1tap);
        hipLaunchKernelGGL(conv_kernel, dim3(512), dim3(512), 0, stream,
                           featT, wk1tap, L);
        hipLaunchKernelGGL(tail_kernel, dim3(1024), dim3(256), 0, stream,
                           feat, L, contrib, wk2p, bk2, wr1, br1, wr2, br2, out);
    } else {
        hipLaunchKernelGGL(main_kernel_mono, dim3(512), dim3(256), 0, stream,
                           feat, wk1, wk2, bk2, wr1, br1, wr2, br2, contrib, out);
    }
}

// Round 5
// 415.962 us; speedup vs baseline: 1.3062x; 1.3062x over previous
//
#include <hip/hip_runtime.h>
#include <math.h>

#define HH 128
#define WW 128

typedef __attribute__((ext_vector_type(8))) short s16x8;
typedef __attribute__((ext_vector_type(8))) _Float16 h16x8;
typedef __attribute__((ext_vector_type(4))) float f32x4;

__device__ __forceinline__ float gelu_f(float x){
    return 0.5f * x * (1.0f + erff(x * 0.70710678118654752440f));
}
// tanh-approx gelu (validated in round 4: output absmax 9.8e-4)
__device__ __forceinline__ float gelu_fast(float x){
    const float u2 = 1.5957691216057308f * x * (1.0f + 0.044715f * x * x);
    const float e  = __expf(u2);
    const float t  = 1.0f - 2.0f / (e + 1.0f);
    return 0.5f * x * (1.0f + t);
}
__device__ __forceinline__ int refl(int v, int n){
    return v < 0 ? -v : (v >= n ? 2*n - 2 - v : v);
}
__device__ __forceinline__ ushort f2bf(float f){
    unsigned int b = __float_as_uint(f);
    unsigned int r = (b + 0x7FFFu + ((b >> 16) & 1u)) >> 16;
    return (ushort)r;
}
__device__ __forceinline__ float bf2f(ushort u){
    return __uint_as_float(((unsigned int)u) << 16);
}

// ---------------------------------------------------------------------------
// featTp_kernel: featTp[b][row][col][c] = bf16(feat[b][c][refl(row-1)][refl(col-1)])
// padded 130x130, channel-minor. One 8-channel 16B chunk per thread.
// ---------------------------------------------------------------------------
__global__ __launch_bounds__(256) void featTp_kernel(
    const float* __restrict__ feat, ushort* __restrict__ featTp)
{
    const int i = blockIdx.x * 256 + threadIdx.x;   // 0..270399
    if (i >= 270400) return;
    const int cb  = i & 7;
    const int col = (i >> 3) % 130;
    const int row = (i / 1040) % 130;
    const int b   = i / 135200;

    const int sr = refl(row - 1, HH);
    const int sc = refl(col - 1, WW);
    const float* __restrict__ src = feat + ((size_t)(b*64 + cb*8) << 14) + (sr << 7) + sc;
    ushort tmp[8];
    #pragma unroll
    for (int j = 0; j < 8; ++j) tmp[j] = f2bf(src[(size_t)j << 14]);
    ushort* dst = featTp + ((((size_t)b*130 + row)*130 + col) << 6) + cb*8;
    *(int4*)dst = *(const int4*)tmp;
}

// ---------------------------------------------------------------------------
// prep_all: 321 blocks.
//   block 0           : m_emb (4 parities) -> contrib[4][128]
//   blocks 1..288     : wk1tap[tap][o][c] bf16
//   blocks 289..320   : wr1h[o][c] fp16 (identity layout convert)
// ---------------------------------------------------------------------------
__global__ __launch_bounds__(256) void prep_all(
    const float* __restrict__ w1m, const float* __restrict__ b1m,
    const float* __restrict__ w2m, const float* __restrict__ b2m,
    const float* __restrict__ wk1, const float* __restrict__ bk1,
    const float* __restrict__ wr1,
    float* __restrict__ contrib, ushort* __restrict__ wk1tap,
    _Float16* __restrict__ wr1h)
{
    const int blk = blockIdx.x;
    const int t = threadIdx.x;

    if (blk == 0){
        __shared__ float m_emb[4][64];
        const int p = t >> 6;
        const int o = t & 63;

        const float du = (p & 1) ? -0.25f : 0.25f;
        const float dv = (p >> 1) ? -0.25f : 0.25f;
        const float mv[5] = {2.0f, du, dv, 0.5f, 0.3f};

        float enc[85];
        #pragma unroll
        for (int f = 0; f < 5; ++f){
            enc[f*17] = mv[f];
            float fr = 3.14159265358979323846f;
            #pragma unroll
            for (int b = 0; b < 8; ++b){
                float xb = mv[f] * fr;
                enc[f*17 + 1 + b] = sinf(xb);
                enc[f*17 + 9 + b] = cosf(xb);
                fr *= 2.0f;
            }
        }

        float acc = b2m[o];
        for (int j = 0; j < 64; ++j){
            float h = b1m[j];
            #pragma unroll
            for (int i = 0; i < 85; ++i) h += enc[i] * w1m[j*85 + i];
            acc += gelu_f(h) * w2m[o*64 + j];
        }
        m_emb[p][o] = acc;
        __syncthreads();

        for (int e = t; e < 512; e += 256){
            const int pp = e >> 7;
            const int oo = e & 127;
            float a = bk1[oo];
            #pragma unroll
            for (int j = 0; j < 64; ++j) a += m_emb[pp][j] * wk1[oo*640 + 576 + j];
            contrib[e] = a;
        }
    } else if (blk <= 288){
        const int i = (blk - 1)*256 + t;      // 0..73727
        if (i < 73728){
            const int c   = i & 63;
            const int o   = (i >> 6) & 127;
            const int tap = i >> 13;
            wk1tap[i] = f2bf(wk1[o*640 + c*9 + tap]);
        }
    } else {
        const int i = (blk - 289)*256 + t;    // 0..8191
        if (i < 8192) wr1h[i] = (_Float16)wr1[i];
    }
}

// ---------------------------------------------------------------------------
// conv_kernel: MFMA conv (K=576) + fused w9 epilogue.
// 512 blocks x 512 threads. Tile: 64 cells (2 rows x 32 cx) x 128 outs.
// Epilogue: per (cell,parity) pair of threads -> gelu(L+contrib) -> wk2 dot
// -> softmax -> w9g[b][cell][p][9].
// ---------------------------------------------------------------------------
__global__ __launch_bounds__(512) void conv_kernel(
    const ushort* __restrict__ featTp,
    const ushort* __restrict__ wk1tap,
    const float* __restrict__ wk2, const float* __restrict__ bk2,
    const float* __restrict__ contrib,
    float* __restrict__ w9g)
{
    __shared__ ushort As[4*34*64];     // staged patch region (c-block XOR swizzle)
    __shared__ float  Ls[64][129];     // logits, +1 pad
    __shared__ float  wk2s[1152];
    __shared__ float  contribs[512];

    const int t   = threadIdx.x;
    const int blk = blockIdx.x;
    const int b   = blk >> 8;
    const int rem = blk & 255;
    const int cy0 = (rem >> 2) * 2;
    const int cx0 = (rem & 3) * 32;

    // ---- stage A from padded featTp: rows cy0..cy0+3, cols cx0..cx0+33 ----
    for (int e = t; e < 1088; e += 512){
        const int r   = e / 272;
        const int rm  = e - r * 272;
        const int col = rm >> 3;
        const int cb  = rm & 7;
        const ushort* src = featTp + ((((size_t)b*130 + cy0 + r)*130 + cx0 + col) << 6) + cb*8;
        const int didx = (r*34 + col)*64 + ((cb ^ (col & 7)) << 3);
        *(int4*)&As[didx] = *(const int4*)src;
    }
    for (int e = t; e < 1152; e += 512) wk2s[e] = wk2[e];
    if (t < 512) contribs[t] = contrib[t];
    __syncthreads();

    const int lane = t & 63;
    const int w    = t >> 6;
    const int wn   = w & 1;          // o half (64 each)
    const int wq   = w >> 1;
    const int cellrow = wq >> 1;     // 0/1
    const int colblk  = (wq & 1) * 16;
    const int l15  = lane & 15;
    const int l4   = lane >> 4;

    f32x4 acc[4];
    #pragma unroll
    for (int n = 0; n < 4; ++n) acc[n] = (f32x4){0.f,0.f,0.f,0.f};

    const int acol = colblk + l15;

    #pragma unroll
    for (int tap = 0; tap < 9; ++tap){
        const int ky = tap / 3;
        const int kx = tap - ky * 3;

        s16x8 bf[2][4];
        #pragma unroll
        for (int ks = 0; ks < 2; ++ks)
            #pragma unroll
            for (int n = 0; n < 4; ++n)
                bf[ks][n] = *(const s16x8*)(wk1tap +
                    (((size_t)tap << 13) + ((wn*64 + n*16 + l15) << 6) + ks*32 + l4*8));

        const int col = acol + kx;
        const int rowbase = (cellrow + ky)*34 + col;
        const int sw = (col & 7);
        #pragma unroll
        for (int ks = 0; ks < 2; ++ks){
            const int cb0 = ks*4 + l4;
            const s16x8 af = *(const s16x8*)&As[rowbase*64 + ((cb0 ^ sw) << 3)];
            #pragma unroll
            for (int n = 0; n < 4; ++n)
                acc[n] = __builtin_amdgcn_mfma_f32_16x16x32_bf16(af, bf[ks][n], acc[n], 0, 0, 0);
        }
    }

    // ---- logits -> LDS ----
    #pragma unroll
    for (int n = 0; n < 4; ++n){
        #pragma unroll
        for (int reg = 0; reg < 4; ++reg){
            const int lc = cellrow*32 + colblk + l4*4 + reg;
            const int o  = wn*64 + n*16 + l15;
            Ls[lc][o] = acc[n][reg];
        }
    }
    __syncthreads();

    // ---- epilogue: 256 (cell,parity) tasks x 2 half-threads ----
    const int task = t >> 1;
    const int half = t & 1;
    const int lc   = task >> 2;
    const int p    = task & 3;

    float w9[9];
    #pragma unroll
    for (int k = 0; k < 9; ++k) w9[k] = 0.0f;

    const int rot = (p*16 + half*8) & 63;     // bank-stagger start
    for (int ii = 0; ii < 64; ++ii){
        const int o = half*64 + ((rot + ii) & 63);
        const float h = gelu_fast(Ls[lc][o] + contribs[p*128 + o]);
        #pragma unroll
        for (int k = 0; k < 9; ++k) w9[k] += wk2s[k*128 + o] * h;
    }
    #pragma unroll
    for (int k = 0; k < 9; ++k) w9[k] += __shfl_xor(w9[k], 1);
    #pragma unroll
    for (int k = 0; k < 9; ++k) w9[k] += bk2[k];

    float mx = w9[0];
    #pragma unroll
    for (int k = 1; k < 9; ++k) mx = fmaxf(mx, w9[k]);
    float sum = 0.0f;
    #pragma unroll
    for (int k = 0; k < 9; ++k){ w9[k] = __expf(w9[k] - mx); sum += w9[k]; }
    const float inv = 1.0f / sum;
    #pragma unroll
    for (int k = 0; k < 9; ++k) w9[k] *= inv;

    const int cellg = (cy0 + (lc >> 5))*128 + cx0 + (lc & 31);
    float* dst = w9g + ((size_t)(b*16384 + cellg)*4 + p)*9;
    if (half == 0){
        dst[0] = w9[0]; dst[1] = w9[1]; dst[2] = w9[2]; dst[3] = w9[3]; dst[4] = w9[4];
    } else {
        dst[5] = w9[5]; dst[6] = w9[6]; dst[7] = w9[7]; dst[8] = w9[8];
    }
}

// ---------------------------------------------------------------------------
// fq_kernel: 1 thread = 1 pixel. fq[c] = sum_k w9[k]*patch[(k*64+c)/9][(k*64+c)%9]
// gathered from padded featTp via precomputed LDS offset table. fp16 out.
// ---------------------------------------------------------------------------
__global__ __launch_bounds__(256) void fq_kernel(
    const ushort* __restrict__ featTp,
    const float* __restrict__ w9g,
    _Float16* __restrict__ fqh)
{
    __shared__ int tbl[576];
    for (int e = threadIdx.x; e < 576; e += 256){
        const int ch  = (e * 58255) >> 19;      // e/9 for e<576
        const int tap = e - 9*ch;
        const int ty  = (tap * 11) >> 5;        // tap/3
        const int tx  = tap - 3*ty;
        tbl[e] = ((ty*130 + tx) << 6) + ch;     // offset in featTp elems
    }
    __syncthreads();

    const int tid = blockIdx.x * 256 + threadIdx.x;
    const int b  = tid >> 16;
    const int qi = tid & 65535;
    const int oy = qi >> 8;
    const int ox = qi & 255;

    int cy = (oy - 1) >> 1; if (cy < 0) cy = 0;
    int cx = (ox - 1) >> 1; if (cx < 0) cx = 0;
    const int p = ((oy & 1) << 1) | (ox & 1);

    const float* wp = w9g + ((size_t)(b*16384 + cy*128 + cx)*4 + p)*9;
    float w9[9];
    #pragma unroll
    for (int k = 0; k < 9; ++k) w9[k] = wp[k];

    const ushort* base = featTp + ((((size_t)b*130 + cy)*130 + cx) << 6);
    _Float16* dst = fqh + ((size_t)tid << 6);

    for (int cg = 0; cg < 16; ++cg){
        f32x4 a = (f32x4){0.f,0.f,0.f,0.f};
        #pragma unroll
        for (int k = 0; k < 9; ++k){
            const int j0 = k*64 + cg*4;
            a[0] += w9[k] * bf2f(base[tbl[j0 + 0]]);
            a[1] += w9[k] * bf2f(base[tbl[j0 + 1]]);
            a[2] += w9[k] * bf2f(base[tbl[j0 + 2]]);
            a[3] += w9[k] * bf2f(base[tbl[j0 + 3]]);
        }
        short4 s;
        s.x = __builtin_bit_cast(short, (_Float16)a[0]);
        s.y = __builtin_bit_cast(short, (_Float16)a[1]);
        s.z = __builtin_bit_cast(short, (_Float16)a[2]);
        s.w = __builtin_bit_cast(short, (_Float16)a[3]);
        *(short4*)(dst + cg*4) = s;
    }
}

// ---------------------------------------------------------------------------
// rgb_kernel: hidden = gelu(fq @ wr1^T + br1) via fp16 MFMA (M=131072,K=64,N=64),
// layer2 (64->3) per-lane partials + shfl reduce. 2048 blocks x 256.
// ---------------------------------------------------------------------------
__global__ __launch_bounds__(256) void rgb_kernel(
    const _Float16* __restrict__ fqh,
    const _Float16* __restrict__ wr1h,
    const float* __restrict__ br1, const float* __restrict__ wr2,
    const float* __restrict__ br2,
    float* __restrict__ out)
{
    const int t    = threadIdx.x;
    const int w    = t >> 6;
    const int lane = t & 63;
    const int l15  = lane & 15;
    const int l4   = lane >> 4;
    const int rowbase = blockIdx.x*64 + w*16;

    const h16x8 a0 = *(const h16x8*)&fqh[(size_t)(rowbase + l15)*64 + l4*8];
    const h16x8 a1 = *(const h16x8*)&fqh[(size_t)(rowbase + l15)*64 + 32 + l4*8];

    f32x4 acc[4];
    #pragma unroll
    for (int n = 0; n < 4; ++n){
        const h16x8 b0 = *(const h16x8*)&wr1h[(n*16 + l15)*64 + l4*8];
        const h16x8 b1 = *(const h16x8*)&wr1h[(n*16 + l15)*64 + 32 + l4*8];
        acc[n] = (f32x4){0.f,0.f,0.f,0.f};
        acc[n] = __builtin_amdgcn_mfma_f32_16x16x32_f16(a0, b0, acc[n], 0, 0, 0);
        acc[n] = __builtin_amdgcn_mfma_f32_16x16x32_f16(a1, b1, acc[n], 0, 0, 0);
    }

    f32x4 br1v, wv0, wv1, wv2;
    #pragma unroll
    for (int n = 0; n < 4; ++n){
        const int col = n*16 + l15;
        br1v[n] = br1[col];
        wv0[n]  = wr2[col];
        wv1[n]  = wr2[64 + col];
        wv2[n]  = wr2[128 + col];
    }
    const float b2r0 = br2[0], b2r1 = br2[1], b2r2 = br2[2];

    #pragma unroll
    for (int reg = 0; reg < 4; ++reg){
        float r0 = 0.f, r1 = 0.f, r2 = 0.f;
        #pragma unroll
        for (int n = 0; n < 4; ++n){
            const float h = gelu_fast(acc[n][reg] + br1v[n]);
            r0 += h * wv0[n];
            r1 += h * wv1[n];
            r2 += h * wv2[n];
        }
        r0 += __shfl_xor(r0, 1); r0 += __shfl_xor(r0, 2); r0 += __shfl_xor(r0, 4); r0 += __shfl_xor(r0, 8);
        r1 += __shfl_xor(r1, 1); r1 += __shfl_xor(r1, 2); r1 += __shfl_xor(r1, 4); r1 += __shfl_xor(r1, 8);
        r2 += __shfl_xor(r2, 1); r2 += __shfl_xor(r2, 2); r2 += __shfl_xor(r2, 4); r2 += __shfl_xor(r2, 8);

        if (l15 == 0){
            const int row = rowbase + l4*4 + reg;
            const int b   = row >> 16;
            const int pix = row & 65535;
            out[((size_t)(b*3 + 0) << 16) + pix] = r0 + b2r0;
            out[((size_t)(b*3 + 1) << 16) + pix] = r1 + b2r1;
            out[((size_t)(b*3 + 2) << 16) + pix] = r2 + b2r2;
        }
    }
}

// ---------------------------------------------------------------------------
// Fallback monolithic kernel (round-1 proven; used only if ws too small)
// ---------------------------------------------------------------------------
__global__ __launch_bounds__(256) void main_kernel_mono(
    const float* __restrict__ feat,
    const float* __restrict__ wk1,
    const float* __restrict__ wk2, const float* __restrict__ bk2,
    const float* __restrict__ wr1, const float* __restrict__ br1,
    const float* __restrict__ wr2, const float* __restrict__ br2,
    const float* __restrict__ contrib,
    float* __restrict__ out)
{
    const int tid = blockIdx.x * 256 + threadIdx.x;
    const int b  = tid >> 16;
    const int qi = tid & 65535;
    const int oy = qi >> 8;
    const int ox = qi & 255;

    int cy = (oy - 1) >> 1; if (cy < 0) cy = 0;
    int cx = (ox - 1) >> 1; if (cx < 0) cx = 0;

    int ry[3], rx[3];
    #pragma unroll
    for (int k = 0; k < 3; ++k){ ry[k] = refl(cy-1+k, HH); rx[k] = refl(cx-1+k, WW); }

    const int p = ((oy & 1) << 1) | (ox & 1);
    const float* __restrict__ fb = feat + ((size_t)b << 20);

    float w9[9];
    #pragma unroll
    for (int k = 0; k < 9; ++k) w9[k] = bk2[k];

    for (int oc = 0; oc < 4; ++oc){
        float acc[32];
        #pragma unroll
        for (int j = 0; j < 32; ++j) acc[j] = contrib[p*128 + oc*32 + j];
        for (int c = 0; c < 64; ++c){
            const float* __restrict__ fc = fb + c * (HH*WW);
            float v[9];
            #pragma unroll
            for (int ky = 0; ky < 3; ++ky){
                const float* __restrict__ frow = fc + ry[ky] * WW;
                #pragma unroll
                for (int kx = 0; kx < 3; ++kx) v[ky*3 + kx] = frow[rx[kx]];
            }
            const float* __restrict__ wrow0 = wk1 + (oc*32) * 640 + c * 9;
            #pragma unroll
            for (int j = 0; j < 32; ++j){
                const float* __restrict__ wrow = wrow0 + j * 640;
                float a = acc[j];
                #pragma unroll
                for (int kk = 0; kk < 9; ++kk) a += v[kk] * wrow[kk];
                acc[j] = a;
            }
        }
        #pragma unroll
        for (int j = 0; j < 32; ++j){
            const float h = gelu_f(acc[j]);
            const int o = oc*32 + j;
            #pragma unroll
            for (int k = 0; k < 9; ++k) w9[k] += h * wk2[k*128 + o];
        }
    }

    float mx = w9[0];
    #pragma unroll
    for (int k = 1; k < 9; ++k) mx = fmaxf(mx, w9[k]);
    float sum = 0.0f;
    #pragma unroll
    for (int k = 0; k < 9; ++k){ w9[k] = expf(w9[k] - mx); sum += w9[k]; }
    const float inv = 1.0f / sum;
    #pragma unroll
    for (int k = 0; k < 9; ++k) w9[k] *= inv;

    float fq[64];
    #pragma unroll
    for (int c = 0; c < 64; ++c){
        float a = 0.0f;
        #pragma unroll
        for (int k = 0; k < 9; ++k){
            const int j  = k*64 + c;
            const int ch = j / 9;
            const int kk = j % 9;
            a += w9[k] * fb[ch*(HH*WW) + ry[kk/3]*WW + rx[kk%3]];
        }
        fq[c] = a;
    }

    float r0 = br2[0], r1 = br2[1], r2 = br2[2];
    for (int o = 0; o < 64; ++o){
        float a = br1[o];
        #pragma unroll
        for (int c = 0; c < 64; ++c) a += fq[c] * wr1[o*64 + c];
        const float h = gelu_f(a);
        r0 += h * wr2[o];
        r1 += h * wr2[64 + o];
        r2 += h * wr2[128 + o];
    }

    const int pix = (oy << 8) | ox;
    out[((size_t)(b*3 + 0) << 16) + pix] = r0;
    out[((size_t)(b*3 + 1) << 16) + pix] = r1;
    out[((size_t)(b*3 + 2) << 16) + pix] = r2;
}

extern "C" void kernel_launch(void* const* d_in, const int* in_sizes, int n_in,
                              void* d_out, int out_size, void* d_ws, size_t ws_size,
                              hipStream_t stream)
{
    const float* feat = (const float*)d_in[0];
    const float* w1m  = (const float*)d_in[1];
    const float* b1m  = (const float*)d_in[2];
    const float* w2m  = (const float*)d_in[3];
    const float* b2m  = (const float*)d_in[4];
    const float* wk1  = (const float*)d_in[5];
    const float* bk1  = (const float*)d_in[6];
    const float* wk2  = (const float*)d_in[7];
    const float* bk2  = (const float*)d_in[8];
    const float* wr1  = (const float*)d_in[9];
    const float* br1  = (const float*)d_in[10];
    const float* wr2  = (const float*)d_in[11];
    const float* br2  = (const float*)d_in[12];

    float* out = (float*)d_out;

    // ws layout (26 MB):
    char* ws = (char*)d_ws;
    float*     contrib = (float*)ws;                       //       0 .. 2048
    ushort*    wk1tap  = (ushort*)(ws + 8192);             //    8192 .. 155648
    _Float16*  wr1h    = (_Float16*)(ws + 155648);         //  155648 .. 172032
    ushort*    featTp  = (ushort*)(ws + 172032);           //  172032 .. 4498432
    float*     w9g     = (float*)(ws + 4498432);           // 4498432 .. 9217024
    _Float16*  fqh     = (_Float16*)(ws + 9217024);        // 9217024 .. 25994240
    const size_t need = 25994240;

    hipLaunchKernelGGL(prep_all, dim3(321), dim3(256), 0, stream,
                       w1m, b1m, w2m, b2m, wk1, bk1, wr1, contrib, wk1tap, wr1h);

    if (ws_size >= need){
        hipLaunchKernelGGL(featTp_kernel, dim3(1057), dim3(256), 0, stream, feat, featTp);
        hipLaunchKernelGGL(conv_kernel, dim3(512), dim3(512), 0, stream,
                           featTp, wk1tap, wk2, bk2, contrib, w9g);
        hipLaunchKernelGGL(fq_kernel, dim3(512), dim3(256), 0, stream,
                           featTp, w9g, fqh);
        hipLaunchKernelGGL(rgb_kernel, dim3(2048), dim3(256), 0, stream,
                           fqh, wr1h, br1, wr2, br2, out);
    } else {
        hipLaunchKernelGGL(main_kernel_mono, dim3(512), dim3(256), 0, stream,
                           feat, wk1, wk2, bk2, wr1, br1, wr2, br2, contrib, out);
    }
}

// Round 6
// 257.778 us; speedup vs baseline: 2.1078x; 1.6136x over previous
//
#include <hip/hip_runtime.h>
#include <math.h>

#define HH 128
#define WW 128

typedef __attribute__((ext_vector_type(8))) short s16x8;
typedef __attribute__((ext_vector_type(8))) _Float16 h16x8;
typedef __attribute__((ext_vector_type(4))) float f32x4;

__device__ __forceinline__ float gelu_f(float x){
    return 0.5f * x * (1.0f + erff(x * 0.70710678118654752440f));
}
// tanh-approx gelu (validated rounds 4-5: output absmax 9.8e-4)
__device__ __forceinline__ float gelu_fast(float x){
    const float u2 = 1.5957691216057308f * x * (1.0f + 0.044715f * x * x);
    const float e  = __expf(u2);
    const float t  = 1.0f - 2.0f / (e + 1.0f);
    return 0.5f * x * (1.0f + t);
}
__device__ __forceinline__ int refl(int v, int n){
    return v < 0 ? -v : (v >= n ? 2*n - 2 - v : v);
}
__device__ __forceinline__ ushort f2bf(float f){
    unsigned int b = __float_as_uint(f);
    unsigned int r = (b + 0x7FFFu + ((b >> 16) & 1u)) >> 16;
    return (ushort)r;
}
__device__ __forceinline__ float bf2f(ushort u){
    return __uint_as_float(((unsigned int)u) << 16);
}

// ---------------------------------------------------------------------------
// featTp_kernel: featTp[b][row][col][c] = bf16(feat[b][c][refl(row-1)][refl(col-1)])
// padded 130x130, channel-minor.
// ---------------------------------------------------------------------------
__global__ __launch_bounds__(256) void featTp_kernel(
    const float* __restrict__ feat, ushort* __restrict__ featTp)
{
    const int i = blockIdx.x * 256 + threadIdx.x;   // 0..270399
    if (i >= 270400) return;
    const int cb  = i & 7;
    const int col = (i >> 3) % 130;
    const int row = (i / 1040) % 130;
    const int b   = i / 135200;

    const int sr = refl(row - 1, HH);
    const int sc = refl(col - 1, WW);
    const float* __restrict__ src = feat + ((size_t)(b*64 + cb*8) << 14) + (sr << 7) + sc;
    ushort tmp[8];
    #pragma unroll
    for (int j = 0; j < 8; ++j) tmp[j] = f2bf(src[(size_t)j << 14]);
    ushort* dst = featTp + ((((size_t)b*130 + row)*130 + col) << 6) + cb*8;
    *(int4*)dst = *(const int4*)tmp;
}

// ---------------------------------------------------------------------------
// prep_all: 321 blocks.
//   block 0           : m_emb (4 parities) -> contrib[4][128]
//   blocks 1..288     : wk1tap[tap][o][c] bf16
//   blocks 289..320   : wr1h[o][c] fp16
// ---------------------------------------------------------------------------
__global__ __launch_bounds__(256) void prep_all(
    const float* __restrict__ w1m, const float* __restrict__ b1m,
    const float* __restrict__ w2m, const float* __restrict__ b2m,
    const float* __restrict__ wk1, const float* __restrict__ bk1,
    const float* __restrict__ wr1,
    float* __restrict__ contrib, ushort* __restrict__ wk1tap,
    _Float16* __restrict__ wr1h)
{
    const int blk = blockIdx.x;
    const int t = threadIdx.x;

    if (blk == 0){
        __shared__ float m_emb[4][64];
        const int p = t >> 6;
        const int o = t & 63;

        const float du = (p & 1) ? -0.25f : 0.25f;
        const float dv = (p >> 1) ? -0.25f : 0.25f;
        const float mv[5] = {2.0f, du, dv, 0.5f, 0.3f};

        float enc[85];
        #pragma unroll
        for (int f = 0; f < 5; ++f){
            enc[f*17] = mv[f];
            float fr = 3.14159265358979323846f;
            #pragma unroll
            for (int b = 0; b < 8; ++b){
                float xb = mv[f] * fr;
                enc[f*17 + 1 + b] = sinf(xb);
                enc[f*17 + 9 + b] = cosf(xb);
                fr *= 2.0f;
            }
        }

        float acc = b2m[o];
        for (int j = 0; j < 64; ++j){
            float h = b1m[j];
            #pragma unroll
            for (int i = 0; i < 85; ++i) h += enc[i] * w1m[j*85 + i];
            acc += gelu_f(h) * w2m[o*64 + j];
        }
        m_emb[p][o] = acc;
        __syncthreads();

        for (int e = t; e < 512; e += 256){
            const int pp = e >> 7;
            const int oo = e & 127;
            float a = bk1[oo];
            #pragma unroll
            for (int j = 0; j < 64; ++j) a += m_emb[pp][j] * wk1[oo*640 + 576 + j];
            contrib[e] = a;
        }
    } else if (blk <= 288){
        const int i = (blk - 1)*256 + t;      // 0..73727
        if (i < 73728){
            const int c   = i & 63;
            const int o   = (i >> 6) & 127;
            const int tap = i >> 13;
            wk1tap[i] = f2bf(wk1[o*640 + c*9 + tap]);
        }
    } else {
        const int i = (blk - 289)*256 + t;    // 0..8191
        if (i < 8192) wr1h[i] = (_Float16)wr1[i];
    }
}

// ---------------------------------------------------------------------------
// conv_kernel: MFMA conv (K=576) + fused w9 epilogue + fused fq gather.
// 512 blocks x 512 threads. Tile: 64 cells (2 rows x 32 cx) x 128 outs.
// Phase 1: MFMA logits -> Ls.  Phase 2: gelu+wk2 dot+softmax -> w9s (LDS).
// Phase 3: fq for all 4 parities from As (LDS) -> fqh global (fp16),
//          with boundary pixel duplication.
// ---------------------------------------------------------------------------
__global__ __launch_bounds__(512) void conv_kernel(
    const ushort* __restrict__ featTp,
    const ushort* __restrict__ wk1tap,
    const float* __restrict__ wk2, const float* __restrict__ bk2,
    const float* __restrict__ contrib,
    _Float16* __restrict__ fqh)
{
    __shared__ ushort As[4*34*64];     // patch region, c-block XOR swizzle
    __shared__ float  Ls[64][129];     // logits, +1 pad
    __shared__ float  wk2s[1152];
    __shared__ float  w9s[256*9];      // softmaxed weights per (cell,parity)
    __shared__ ushort tbl[576];        // packed (ch<<9)|(rc<<2)|tx

    const int t   = threadIdx.x;
    const int blk = blockIdx.x;
    const int b   = blk >> 8;
    const int rem = blk & 255;
    const int cy0 = (rem >> 2) * 2;
    const int cx0 = (rem & 3) * 32;

    // ---- stage A from padded featTp: rows cy0..cy0+3, cols cx0..cx0+33 ----
    for (int e = t; e < 1088; e += 512){
        const int r   = e / 272;
        const int rm  = e - r * 272;
        const int col = rm >> 3;
        const int cb  = rm & 7;
        const ushort* src = featTp + ((((size_t)b*130 + cy0 + r)*130 + cx0 + col) << 6) + cb*8;
        const int didx = (r*34 + col)*64 + ((cb ^ (col & 7)) << 3);
        *(int4*)&As[didx] = *(const int4*)src;
    }
    for (int e = t; e < 1152; e += 512) wk2s[e] = wk2[e];
    for (int e = t; e < 576; e += 512){
        const int ch  = e / 9;
        const int tap = e - 9*ch;
        const int ty  = tap / 3;
        const int tx  = tap - 3*ty;
        tbl[e] = (ushort)((ch << 9) | ((ty*34 + tx) << 2) | tx);
    }
    __syncthreads();

    // ---- Phase 1: MFMA ----
    {
        const int lane = t & 63;
        const int w    = t >> 6;
        const int wn   = w & 1;          // o half (64 each)
        const int wq   = w >> 1;
        const int cellrow = wq >> 1;     // 0/1
        const int colblk  = (wq & 1) * 16;
        const int l15  = lane & 15;
        const int l4   = lane >> 4;

        f32x4 acc[4];
        #pragma unroll
        for (int n = 0; n < 4; ++n) acc[n] = (f32x4){0.f,0.f,0.f,0.f};

        const int acol = colblk + l15;

        #pragma unroll
        for (int tap = 0; tap < 9; ++tap){
            const int ky = tap / 3;
            const int kx = tap - ky * 3;

            s16x8 bf[2][4];
            #pragma unroll
            for (int ks = 0; ks < 2; ++ks)
                #pragma unroll
                for (int n = 0; n < 4; ++n)
                    bf[ks][n] = *(const s16x8*)(wk1tap +
                        (((size_t)tap << 13) + ((wn*64 + n*16 + l15) << 6) + ks*32 + l4*8));

            const int col = acol + kx;
            const int rowbase = (cellrow + ky)*34 + col;
            const int sw = (col & 7);
            #pragma unroll
            for (int ks = 0; ks < 2; ++ks){
                const int cb0 = ks*4 + l4;
                const s16x8 af = *(const s16x8*)&As[rowbase*64 + ((cb0 ^ sw) << 3)];
                #pragma unroll
                for (int n = 0; n < 4; ++n)
                    acc[n] = __builtin_amdgcn_mfma_f32_16x16x32_bf16(af, bf[ks][n], acc[n], 0, 0, 0);
            }
        }

        // logits -> LDS
        #pragma unroll
        for (int n = 0; n < 4; ++n){
            #pragma unroll
            for (int reg = 0; reg < 4; ++reg){
                const int lc = cellrow*32 + colblk + l4*4 + reg;
                const int o  = wn*64 + n*16 + l15;
                Ls[lc][o] = acc[n][reg];
            }
        }
    }
    __syncthreads();

    // ---- Phase 2: w9 (gelu + wk2 dot + softmax) -> w9s ----
    {
        const int task = t >> 1;         // (lc,p): lc=task>>2, p=task&3
        const int half = t & 1;
        const int lc   = task >> 2;
        const int p    = task & 3;

        float w9[9];
        #pragma unroll
        for (int k = 0; k < 9; ++k) w9[k] = 0.0f;

        const int rot = (p*16 + half*8) & 63;     // bank stagger
        for (int ii = 0; ii < 64; ++ii){
            const int o = half*64 + ((rot + ii) & 63);
            const float h = gelu_fast(Ls[lc][o] + contrib[p*128 + o]);
            #pragma unroll
            for (int k = 0; k < 9; ++k) w9[k] += wk2s[k*128 + o] * h;
        }
        #pragma unroll
        for (int k = 0; k < 9; ++k) w9[k] += __shfl_xor(w9[k], 1);
        #pragma unroll
        for (int k = 0; k < 9; ++k) w9[k] += bk2[k];

        float mx = w9[0];
        #pragma unroll
        for (int k = 1; k < 9; ++k) mx = fmaxf(mx, w9[k]);
        float sum = 0.0f;
        #pragma unroll
        for (int k = 0; k < 9; ++k){ w9[k] = __expf(w9[k] - mx); sum += w9[k]; }
        const float inv = 1.0f / sum;
        #pragma unroll
        for (int k = 0; k < 9; ++k) w9[k] *= inv;

        if (half == 0){
            w9s[task*9+0] = w9[0]; w9s[task*9+1] = w9[1]; w9s[task*9+2] = w9[2];
            w9s[task*9+3] = w9[3]; w9s[task*9+4] = w9[4];
        } else {
            w9s[task*9+5] = w9[5]; w9s[task*9+6] = w9[6];
            w9s[task*9+7] = w9[7]; w9s[task*9+8] = w9[8];
        }
    }
    __syncthreads();

    // ---- Phase 3: fq for all 4 parities; write fqh (fp16, pixel-indexed) ----
    {
        const int ci  = t >> 3;          // cell in block 0..63
        const int sub = t & 7;           // owns channels [8*sub, 8*sub+8)
        const int rr  = ci >> 5;         // cell row in block (0/1)
        const int x   = ci & 31;         // cell col in block
        const int base_rc = rr*34 + x;
        const int c0 = sub*8;

        float w9r[4][9];
        #pragma unroll
        for (int p = 0; p < 4; ++p)
            #pragma unroll
            for (int k = 0; k < 9; ++k)
                w9r[p][k] = w9s[(ci*4 + p)*9 + k];

        float fqa[4][8];
        #pragma unroll
        for (int p = 0; p < 4; ++p)
            #pragma unroll
            for (int i = 0; i < 8; ++i) fqa[p][i] = 0.0f;

        #pragma unroll
        for (int k = 0; k < 9; ++k){
            #pragma unroll
            for (int i = 0; i < 8; ++i){
                const int e  = tbl[k*64 + c0 + i];
                const int tx = e & 3;
                const int rc = (e >> 2) & 127;
                const int ch = e >> 9;
                const int col = x + tx;
                const int aidx = ((base_rc + rc) << 6)
                               + (((ch >> 3) ^ (col & 7)) << 3) + (ch & 7);
                const float v = bf2f(As[aidx]);
                fqa[0][i] += w9r[0][k] * v;
                fqa[1][i] += w9r[1][k] * v;
                fqa[2][i] += w9r[2][k] * v;
                fqa[3][i] += w9r[3][k] * v;
            }
        }

        const int gy = cy0 + rr;
        const int gx = cx0 + x;

        #pragma unroll
        for (int p = 0; p < 4; ++p){
            const int py = p >> 1, px = p & 1;
            h16x8 hv;
            #pragma unroll
            for (int i = 0; i < 8; ++i) hv[i] = (_Float16)fqa[p][i];

            const int oy0 = 2*gy + 2 - py;
            const int ox0 = 2*gx + 2 - px;
            const bool y0ok = (py == 1) || (gy < 127);
            const bool x0ok = (px == 1) || (gx < 127);
            const bool yEx  = (gy == 0) && (py == 0);
            const bool xEx  = (gx == 0) && (px == 0);

            if (y0ok && x0ok)
                *(h16x8*)(fqh + (((size_t)((b << 16) | (oy0 << 8) | ox0)) << 6) + c0) = hv;
            if (y0ok && xEx)
                *(h16x8*)(fqh + (((size_t)((b << 16) | (oy0 << 8))) << 6) + c0) = hv;
            if (yEx && x0ok)
                *(h16x8*)(fqh + (((size_t)((b << 16) | ox0)) << 6) + c0) = hv;
            if (yEx && xEx)
                *(h16x8*)(fqh + (((size_t)(b << 16)) << 6) + c0) = hv;
        }
    }
}

// ---------------------------------------------------------------------------
// rgb_kernel: hidden = gelu(fq @ wr1^T + br1) via fp16 MFMA, layer2 via shfl.
// ---------------------------------------------------------------------------
__global__ __launch_bounds__(256) void rgb_kernel(
    const _Float16* __restrict__ fqh,
    const _Float16* __restrict__ wr1h,
    const float* __restrict__ br1, const float* __restrict__ wr2,
    const float* __restrict__ br2,
    float* __restrict__ out)
{
    const int t    = threadIdx.x;
    const int w    = t >> 6;
    const int lane = t & 63;
    const int l15  = lane & 15;
    const int l4   = lane >> 4;
    const int rowbase = blockIdx.x*64 + w*16;

    const h16x8 a0 = *(const h16x8*)&fqh[(size_t)(rowbase + l15)*64 + l4*8];
    const h16x8 a1 = *(const h16x8*)&fqh[(size_t)(rowbase + l15)*64 + 32 + l4*8];

    f32x4 acc[4];
    #pragma unroll
    for (int n = 0; n < 4; ++n){
        const h16x8 b0 = *(const h16x8*)&wr1h[(n*16 + l15)*64 + l4*8];
        const h16x8 b1 = *(const h16x8*)&wr1h[(n*16 + l15)*64 + 32 + l4*8];
        acc[n] = (f32x4){0.f,0.f,0.f,0.f};
        acc[n] = __builtin_amdgcn_mfma_f32_16x16x32_f16(a0, b0, acc[n], 0, 0, 0);
        acc[n] = __builtin_amdgcn_mfma_f32_16x16x32_f16(a1, b1, acc[n], 0, 0, 0);
    }

    f32x4 br1v, wv0, wv1, wv2;
    #pragma unroll
    for (int n = 0; n < 4; ++n){
        const int col = n*16 + l15;
        br1v[n] = br1[col];
        wv0[n]  = wr2[col];
        wv1[n]  = wr2[64 + col];
        wv2[n]  = wr2[128 + col];
    }
    const float b2r0 = br2[0], b2r1 = br2[1], b2r2 = br2[2];

    #pragma unroll
    for (int reg = 0; reg < 4; ++reg){
        float r0 = 0.f, r1 = 0.f, r2 = 0.f;
        #pragma unroll
        for (int n = 0; n < 4; ++n){
            const float h = gelu_fast(acc[n][reg] + br1v[n]);
            r0 += h * wv0[n];
            r1 += h * wv1[n];
            r2 += h * wv2[n];
        }
        r0 += __shfl_xor(r0, 1); r0 += __shfl_xor(r0, 2); r0 += __shfl_xor(r0, 4); r0 += __shfl_xor(r0, 8);
        r1 += __shfl_xor(r1, 1); r1 += __shfl_xor(r1, 2); r1 += __shfl_xor(r1, 4); r1 += __shfl_xor(r1, 8);
        r2 += __shfl_xor(r2, 1); r2 += __shfl_xor(r2, 2); r2 += __shfl_xor(r2, 4); r2 += __shfl_xor(r2, 8);

        if (l15 == 0){
            const int row = rowbase + l4*4 + reg;
            const int b   = row >> 16;
            const int pix = row & 65535;
            out[((size_t)(b*3 + 0) << 16) + pix] = r0 + b2r0;
            out[((size_t)(b*3 + 1) << 16) + pix] = r1 + b2r1;
            out[((size_t)(b*3 + 2) << 16) + pix] = r2 + b2r2;
        }
    }
}

// ---------------------------------------------------------------------------
// Fallback monolithic kernel (round-1 proven; used only if ws too small)
// ---------------------------------------------------------------------------
__global__ __launch_bounds__(256) void main_kernel_mono(
    const float* __restrict__ feat,
    const float* __restrict__ wk1,
    const float* __restrict__ wk2, const float* __restrict__ bk2,
    const float* __restrict__ wr1, const float* __restrict__ br1,
    const float* __restrict__ wr2, const float* __restrict__ br2,
    const float* __restrict__ contrib,
    float* __restrict__ out)
{
    const int tid = blockIdx.x * 256 + threadIdx.x;
    const int b  = tid >> 16;
    const int qi = tid & 65535;
    const int oy = qi >> 8;
    const int ox = qi & 255;

    int cy = (oy - 1) >> 1; if (cy < 0) cy = 0;
    int cx = (ox - 1) >> 1; if (cx < 0) cx = 0;

    int ry[3], rx[3];
    #pragma unroll
    for (int k = 0; k < 3; ++k){ ry[k] = refl(cy-1+k, HH); rx[k] = refl(cx-1+k, WW); }

    const int p = ((oy & 1) << 1) | (ox & 1);
    const float* __restrict__ fb = feat + ((size_t)b << 20);

    float w9[9];
    #pragma unroll
    for (int k = 0; k < 9; ++k) w9[k] = bk2[k];

    for (int oc = 0; oc < 4; ++oc){
        float acc[32];
        #pragma unroll
        for (int j = 0; j < 32; ++j) acc[j] = contrib[p*128 + oc*32 + j];
        for (int c = 0; c < 64; ++c){
            const float* __restrict__ fc = fb + c * (HH*WW);
            float v[9];
            #pragma unroll
            for (int ky = 0; ky < 3; ++ky){
                const float* __restrict__ frow = fc + ry[ky] * WW;
                #pragma unroll
                for (int kx = 0; kx < 3; ++kx) v[ky*3 + kx] = frow[rx[kx]];
            }
            const float* __restrict__ wrow0 = wk1 + (oc*32) * 640 + c * 9;
            #pragma unroll
            for (int j = 0; j < 32; ++j){
                const float* __restrict__ wrow = wrow0 + j * 640;
                float a = acc[j];
                #pragma unroll
                for (int kk = 0; kk < 9; ++kk) a += v[kk] * wrow[kk];
                acc[j] = a;
            }
        }
        #pragma unroll
        for (int j = 0; j < 32; ++j){
            const float h = gelu_f(acc[j]);
            const int o = oc*32 + j;
            #pragma unroll
            for (int k = 0; k < 9; ++k) w9[k] += h * wk2[k*128 + o];
        }
    }

    float mx = w9[0];
    #pragma unroll
    for (int k = 1; k < 9; ++k) mx = fmaxf(mx, w9[k]);
    float sum = 0.0f;
    #pragma unroll
    for (int k = 0; k < 9; ++k){ w9[k] = expf(w9[k] - mx); sum += w9[k]; }
    const float inv = 1.0f / sum;
    #pragma unroll
    for (int k = 0; k < 9; ++k) w9[k] *= inv;

    float fq[64];
    #pragma unroll
    for (int c = 0; c < 64; ++c){
        float a = 0.0f;
        #pragma unroll
        for (int k = 0; k < 9; ++k){
            const int j  = k*64 + c;
            const int ch = j / 9;
            const int kk = j % 9;
            a += w9[k] * fb[ch*(HH*WW) + ry[kk/3]*WW + rx[kk%3]];
        }
        fq[c] = a;
    }

    float r0 = br2[0], r1 = br2[1], r2 = br2[2];
    for (int o = 0; o < 64; ++o){
        float a = br1[o];
        #pragma unroll
        for (int c = 0; c < 64; ++c) a += fq[c] * wr1[o*64 + c];
        const float h = gelu_f(a);
        r0 += h * wr2[o];
        r1 += h * wr2[64 + o];
        r2 += h * wr2[128 + o];
    }

    const int pix = (oy << 8) | ox;
    out[((size_t)(b*3 + 0) << 16) + pix] = r0;
    out[((size_t)(b*3 + 1) << 16) + pix] = r1;
    out[((size_t)(b*3 + 2) << 16) + pix] = r2;
}

extern "C" void kernel_launch(void* const* d_in, const int* in_sizes, int n_in,
                              void* d_out, int out_size, void* d_ws, size_t ws_size,
                              hipStream_t stream)
{
    const float* feat = (const float*)d_in[0];
    const float* w1m  = (const float*)d_in[1];
    const float* b1m  = (const float*)d_in[2];
    const float* w2m  = (const float*)d_in[3];
    const float* b2m  = (const float*)d_in[4];
    const float* wk1  = (const float*)d_in[5];
    const float* bk1  = (const float*)d_in[6];
    const float* wk2  = (const float*)d_in[7];
    const float* bk2  = (const float*)d_in[8];
    const float* wr1  = (const float*)d_in[9];
    const float* br1  = (const float*)d_in[10];
    const float* wr2  = (const float*)d_in[11];
    const float* br2  = (const float*)d_in[12];

    float* out = (float*)d_out;

    // ws layout (~21 MB):
    char* ws = (char*)d_ws;
    float*     contrib = (float*)ws;                       //       0 .. 2048
    ushort*    wk1tap  = (ushort*)(ws + 8192);             //    8192 .. 155648
    _Float16*  wr1h    = (_Float16*)(ws + 155648);         //  155648 .. 172032
    ushort*    featTp  = (ushort*)(ws + 172032);           //  172032 .. 4498432
    _Float16*  fqh     = (_Float16*)(ws + 4498432);        // 4498432 .. 21275648
    const size_t need = 21275648;

    hipLaunchKernelGGL(prep_all, dim3(321), dim3(256), 0, stream,
                       w1m, b1m, w2m, b2m, wk1, bk1, wr1, contrib, wk1tap, wr1h);

    if (ws_size >= need){
        hipLaunchKernelGGL(featTp_kernel, dim3(1057), dim3(256), 0, stream, feat, featTp);
        hipLaunchKernelGGL(conv_kernel, dim3(512), dim3(512), 0, stream,
                           featTp, wk1tap, wk2, bk2, contrib, fqh);
        hipLaunchKernelGGL(rgb_kernel, dim3(2048), dim3(256), 0, stream,
                           fqh, wr1h, br1, wr2, br2, out);
    } else {
        hipLaunchKernelGGL(main_kernel_mono, dim3(512), dim3(256), 0, stream,
                           feat, wk1, wk2, bk2, wr1, br1, wr2, br2, contrib, out);
    }
}

// Round 7
// 184.488 us; speedup vs baseline: 2.9452x; 1.3973x over previous
//
#include <hip/hip_runtime.h>
#include <math.h>

#define HH 128
#define WW 128

typedef __attribute__((ext_vector_type(8))) short s16x8;
typedef __attribute__((ext_vector_type(8))) _Float16 h16x8;
typedef __attribute__((ext_vector_type(4))) float f32x4;

__device__ __forceinline__ float gelu_f(float x){
    return 0.5f * x * (1.0f + erff(x * 0.70710678118654752440f));
}
// tanh-approx gelu (validated rounds 4-6: output absmax 9.8e-4)
__device__ __forceinline__ float gelu_fast(float x){
    const float u2 = 1.5957691216057308f * x * (1.0f + 0.044715f * x * x);
    const float e  = __expf(u2);
    const float t  = 1.0f - 2.0f / (e + 1.0f);
    return 0.5f * x * (1.0f + t);
}
__device__ __forceinline__ int refl(int v, int n){
    return v < 0 ? -v : (v >= n ? 2*n - 2 - v : v);
}
__device__ __forceinline__ ushort f2bf(float f){
    unsigned int b = __float_as_uint(f);
    unsigned int r = (b + 0x7FFFu + ((b >> 16) & 1u)) >> 16;
    return (ushort)r;
}
__device__ __forceinline__ float bf2f(ushort u){
    return __uint_as_float(((unsigned int)u) << 16);
}

// ---------------------------------------------------------------------------
// featTp_kernel: featTp[b][row][col][c] = bf16(feat[b][c][refl(row-1)][refl(col-1)])
// padded 130x130, channel-minor.
// ---------------------------------------------------------------------------
__global__ __launch_bounds__(256) void featTp_kernel(
    const float* __restrict__ feat, ushort* __restrict__ featTp)
{
    const int i = blockIdx.x * 256 + threadIdx.x;   // 0..270399
    if (i >= 270400) return;
    const int cb  = i & 7;
    const int col = (i >> 3) % 130;
    const int row = (i / 1040) % 130;
    const int b   = i / 135200;

    const int sr = refl(row - 1, HH);
    const int sc = refl(col - 1, WW);
    const float* __restrict__ src = feat + ((size_t)(b*64 + cb*8) << 14) + (sr << 7) + sc;
    ushort tmp[8];
    #pragma unroll
    for (int j = 0; j < 8; ++j) tmp[j] = f2bf(src[(size_t)j << 14]);
    ushort* dst = featTp + ((((size_t)b*130 + row)*130 + col) << 6) + cb*8;
    *(int4*)dst = *(const int4*)tmp;
}

// ---------------------------------------------------------------------------
// prep_all: 321 blocks.
//   block 0           : meta-MLP, PARALLELIZED: stage1 thread=(p,j) computes
//                       gelu hidden; stage2 thread=(p,o) computes m_emb;
//                       stage3 contrib[p][o] = bk1[o] + wk1[o,576:].m_emb[p]
//   blocks 1..288     : wk1tap[tap][o][c] bf16
//   blocks 289..320   : wr1h[o][c] fp16
// ---------------------------------------------------------------------------
__global__ __launch_bounds__(256) void prep_all(
    const float* __restrict__ w1m, const float* __restrict__ b1m,
    const float* __restrict__ w2m, const float* __restrict__ b2m,
    const float* __restrict__ wk1, const float* __restrict__ bk1,
    const float* __restrict__ wr1,
    float* __restrict__ contrib, ushort* __restrict__ wk1tap,
    _Float16* __restrict__ wr1h)
{
    const int blk = blockIdx.x;
    const int t = threadIdx.x;

    if (blk == 0){
        __shared__ float hs[4][64];
        __shared__ float m_emb[4][64];
        const int p = t >> 6;
        const int j = t & 63;   // stage1: hidden unit; stage2: output unit

        // ---- stage 1: h[p][j] = gelu(b1m[j] + enc(p) . w1m[j]) ----
        const float du = (p & 1) ? -0.25f : 0.25f;
        const float dv = (p >> 1) ? -0.25f : 0.25f;
        const float mv[5] = {2.0f, du, dv, 0.5f, 0.3f};

        float enc[85];
        #pragma unroll
        for (int f = 0; f < 5; ++f){
            enc[f*17] = mv[f];
            float fr = 3.14159265358979323846f;
            #pragma unroll
            for (int b = 0; b < 8; ++b){
                float xb = mv[f] * fr;
                enc[f*17 + 1 + b] = sinf(xb);
                enc[f*17 + 9 + b] = cosf(xb);
                fr *= 2.0f;
            }
        }

        float h = b1m[j];
        const float* __restrict__ wrow = w1m + j*85;
        #pragma unroll
        for (int i = 0; i < 85; ++i) h += enc[i] * wrow[i];
        hs[p][j] = gelu_f(h);
        __syncthreads();

        // ---- stage 2: m_emb[p][o] = b2m[o] + sum_j hs[p][j]*w2m[o][j] ----
        {
            const int o = j;
            float acc = b2m[o];
            const float* __restrict__ w2row = w2m + o*64;
            #pragma unroll
            for (int jj = 0; jj < 64; ++jj) acc += hs[p][jj] * w2row[jj];
            m_emb[p][o] = acc;
        }
        __syncthreads();

        // ---- stage 3: contrib ----
        for (int e = t; e < 512; e += 256){
            const int pp = e >> 7;
            const int oo = e & 127;
            float a = bk1[oo];
            #pragma unroll
            for (int jj = 0; jj < 64; ++jj) a += m_emb[pp][jj] * wk1[oo*640 + 576 + jj];
            contrib[e] = a;
        }
    } else if (blk <= 288){
        const int i = (blk - 1)*256 + t;      // 0..73727
        if (i < 73728){
            const int c   = i & 63;
            const int o   = (i >> 6) & 127;
            const int tap = i >> 13;
            wk1tap[i] = f2bf(wk1[o*640 + c*9 + tap]);
        }
    } else {
        const int i = (blk - 289)*256 + t;    // 0..8191
        if (i < 8192) wr1h[i] = (_Float16)wr1[i];
    }
}

// ---------------------------------------------------------------------------
// conv_kernel: MFMA conv (K=576) + fused w9 epilogue + fused fq gather.
// 512 blocks x 512 threads. Tile: 64 cells (2 rows x 32 cx) x 128 outs.
// ---------------------------------------------------------------------------
__global__ __launch_bounds__(512) void conv_kernel(
    const ushort* __restrict__ featTp,
    const ushort* __restrict__ wk1tap,
    const float* __restrict__ wk2, const float* __restrict__ bk2,
    const float* __restrict__ contrib,
    _Float16* __restrict__ fqh)
{
    __shared__ ushort As[4*34*64];     // patch region, c-block XOR swizzle
    __shared__ float  Ls[64][129];     // logits, +1 pad
    __shared__ float  wk2s[1152];
    __shared__ float  w9s[256*9];      // softmaxed weights per (cell,parity)
    __shared__ ushort tbl[576];        // packed (ch<<9)|(rc<<2)|tx

    const int t   = threadIdx.x;
    const int blk = blockIdx.x;
    const int b   = blk >> 8;
    const int rem = blk & 255;
    const int cy0 = (rem >> 2) * 2;
    const int cx0 = (rem & 3) * 32;

    // ---- stage A from padded featTp: rows cy0..cy0+3, cols cx0..cx0+33 ----
    for (int e = t; e < 1088; e += 512){
        const int r   = e / 272;
        const int rm  = e - r * 272;
        const int col = rm >> 3;
        const int cb  = rm & 7;
        const ushort* src = featTp + ((((size_t)b*130 + cy0 + r)*130 + cx0 + col) << 6) + cb*8;
        const int didx = (r*34 + col)*64 + ((cb ^ (col & 7)) << 3);
        *(int4*)&As[didx] = *(const int4*)src;
    }
    for (int e = t; e < 1152; e += 512) wk2s[e] = wk2[e];
    for (int e = t; e < 576; e += 512){
        const int ch  = e / 9;
        const int tap = e - 9*ch;
        const int ty  = tap / 3;
        const int tx  = tap - 3*ty;
        tbl[e] = (ushort)((ch << 9) | ((ty*34 + tx) << 2) | tx);
    }
    __syncthreads();

    // ---- Phase 1: MFMA ----
    {
        const int lane = t & 63;
        const int w    = t >> 6;
        const int wn   = w & 1;          // o half (64 each)
        const int wq   = w >> 1;
        const int cellrow = wq >> 1;     // 0/1
        const int colblk  = (wq & 1) * 16;
        const int l15  = lane & 15;
        const int l4   = lane >> 4;

        f32x4 acc[4];
        #pragma unroll
        for (int n = 0; n < 4; ++n) acc[n] = (f32x4){0.f,0.f,0.f,0.f};

        const int acol = colblk + l15;

        #pragma unroll
        for (int tap = 0; tap < 9; ++tap){
            const int ky = tap / 3;
            const int kx = tap - ky * 3;

            s16x8 bf[2][4];
            #pragma unroll
            for (int ks = 0; ks < 2; ++ks)
                #pragma unroll
                for (int n = 0; n < 4; ++n)
                    bf[ks][n] = *(const s16x8*)(wk1tap +
                        (((size_t)tap << 13) + ((wn*64 + n*16 + l15) << 6) + ks*32 + l4*8));

            const int col = acol + kx;
            const int rowbase = (cellrow + ky)*34 + col;
            const int sw = (col & 7);
            #pragma unroll
            for (int ks = 0; ks < 2; ++ks){
                const int cb0 = ks*4 + l4;
                const s16x8 af = *(const s16x8*)&As[rowbase*64 + ((cb0 ^ sw) << 3)];
                #pragma unroll
                for (int n = 0; n < 4; ++n)
                    acc[n] = __builtin_amdgcn_mfma_f32_16x16x32_bf16(af, bf[ks][n], acc[n], 0, 0, 0);
            }
        }

        // logits -> LDS
        #pragma unroll
        for (int n = 0; n < 4; ++n){
            #pragma unroll
            for (int reg = 0; reg < 4; ++reg){
                const int lc = cellrow*32 + colblk + l4*4 + reg;
                const int o  = wn*64 + n*16 + l15;
                Ls[lc][o] = acc[n][reg];
            }
        }
    }
    __syncthreads();

    // ---- Phase 2: w9 (gelu + wk2 dot + softmax) -> w9s ----
    {
        const int task = t >> 1;         // (lc,p): lc=task>>2, p=task&3
        const int half = t & 1;
        const int lc   = task >> 2;
        const int p    = task & 3;

        float w9[9];
        #pragma unroll
        for (int k = 0; k < 9; ++k) w9[k] = 0.0f;

        const int rot = (p*16 + half*8) & 63;     // bank stagger
        for (int ii = 0; ii < 64; ++ii){
            const int o = half*64 + ((rot + ii) & 63);
            const float h = gelu_fast(Ls[lc][o] + contrib[p*128 + o]);
            #pragma unroll
            for (int k = 0; k < 9; ++k) w9[k] += wk2s[k*128 + o] * h;
        }
        #pragma unroll
        for (int k = 0; k < 9; ++k) w9[k] += __shfl_xor(w9[k], 1);
        #pragma unroll
        for (int k = 0; k < 9; ++k) w9[k] += bk2[k];

        float mx = w9[0];
        #pragma unroll
        for (int k = 1; k < 9; ++k) mx = fmaxf(mx, w9[k]);
        float sum = 0.0f;
        #pragma unroll
        for (int k = 0; k < 9; ++k){ w9[k] = __expf(w9[k] - mx); sum += w9[k]; }
        const float inv = 1.0f / sum;
        #pragma unroll
        for (int k = 0; k < 9; ++k) w9[k] *= inv;

        if (half == 0){
            w9s[task*9+0] = w9[0]; w9s[task*9+1] = w9[1]; w9s[task*9+2] = w9[2];
            w9s[task*9+3] = w9[3]; w9s[task*9+4] = w9[4];
        } else {
            w9s[task*9+5] = w9[5]; w9s[task*9+6] = w9[6];
            w9s[task*9+7] = w9[7]; w9s[task*9+8] = w9[8];
        }
    }
    __syncthreads();

    // ---- Phase 3: fq for all 4 parities; write fqh (fp16, pixel-indexed) ----
    {
        const int ci  = t >> 3;          // cell in block 0..63
        const int sub = t & 7;           // owns channels [8*sub, 8*sub+8)
        const int rr  = ci >> 5;         // cell row in block (0/1)
        const int x   = ci & 31;         // cell col in block
        const int base_rc = rr*34 + x;
        const int c0 = sub*8;

        float w9r[4][9];
        #pragma unroll
        for (int p = 0; p < 4; ++p)
            #pragma unroll
            for (int k = 0; k < 9; ++k)
                w9r[p][k] = w9s[(ci*4 + p)*9 + k];

        float fqa[4][8];
        #pragma unroll
        for (int p = 0; p < 4; ++p)
            #pragma unroll
            for (int i = 0; i < 8; ++i) fqa[p][i] = 0.0f;

        #pragma unroll
        for (int k = 0; k < 9; ++k){
            #pragma unroll
            for (int i = 0; i < 8; ++i){
                const int e  = tbl[k*64 + c0 + i];
                const int tx = e & 3;
                const int rc = (e >> 2) & 127;
                const int ch = e >> 9;
                const int col = x + tx;
                const int aidx = ((base_rc + rc) << 6)
                               + (((ch >> 3) ^ (col & 7)) << 3) + (ch & 7);
                const float v = bf2f(As[aidx]);
                fqa[0][i] += w9r[0][k] * v;
                fqa[1][i] += w9r[1][k] * v;
                fqa[2][i] += w9r[2][k] * v;
                fqa[3][i] += w9r[3][k] * v;
            }
        }

        const int gy = cy0 + rr;
        const int gx = cx0 + x;

        #pragma unroll
        for (int p = 0; p < 4; ++p){
            const int py = p >> 1, px = p & 1;
            h16x8 hv;
            #pragma unroll
            for (int i = 0; i < 8; ++i) hv[i] = (_Float16)fqa[p][i];

            const int oy0 = 2*gy + 2 - py;
            const int ox0 = 2*gx + 2 - px;
            const bool y0ok = (py == 1) || (gy < 127);
            const bool x0ok = (px == 1) || (gx < 127);
            const bool yEx  = (gy == 0) && (py == 0);
            const bool xEx  = (gx == 0) && (px == 0);

            if (y0ok && x0ok)
                *(h16x8*)(fqh + (((size_t)((b << 16) | (oy0 << 8) | ox0)) << 6) + c0) = hv;
            if (y0ok && xEx)
                *(h16x8*)(fqh + (((size_t)((b << 16) | (oy0 << 8))) << 6) + c0) = hv;
            if (yEx && x0ok)
                *(h16x8*)(fqh + (((size_t)((b << 16) | ox0)) << 6) + c0) = hv;
            if (yEx && xEx)
                *(h16x8*)(fqh + (((size_t)(b << 16)) << 6) + c0) = hv;
        }
    }
}

// ---------------------------------------------------------------------------
// rgb_kernel: hidden = gelu(fq @ wr1^T + br1) via fp16 MFMA, layer2 via shfl.
// ---------------------------------------------------------------------------
__global__ __launch_bounds__(256) void rgb_kernel(
    const _Float16* __restrict__ fqh,
    const _Float16* __restrict__ wr1h,
    const float* __restrict__ br1, const float* __restrict__ wr2,
    const float* __restrict__ br2,
    float* __restrict__ out)
{
    const int t    = threadIdx.x;
    const int w    = t >> 6;
    const int lane = t & 63;
    const int l15  = lane & 15;
    const int l4   = lane >> 4;
    const int rowbase = blockIdx.x*64 + w*16;

    const h16x8 a0 = *(const h16x8*)&fqh[(size_t)(rowbase + l15)*64 + l4*8];
    const h16x8 a1 = *(const h16x8*)&fqh[(size_t)(rowbase + l15)*64 + 32 + l4*8];

    f32x4 acc[4];
    #pragma unroll
    for (int n = 0; n < 4; ++n){
        const h16x8 b0 = *(const h16x8*)&wr1h[(n*16 + l15)*64 + l4*8];
        const h16x8 b1 = *(const h16x8*)&wr1h[(n*16 + l15)*64 + 32 + l4*8];
        acc[n] = (f32x4){0.f,0.f,0.f,0.f};
        acc[n] = __builtin_amdgcn_mfma_f32_16x16x32_f16(a0, b0, acc[n], 0, 0, 0);
        acc[n] = __builtin_amdgcn_mfma_f32_16x16x32_f16(a1, b1, acc[n], 0, 0, 0);
    }

    f32x4 br1v, wv0, wv1, wv2;
    #pragma unroll
    for (int n = 0; n < 4; ++n){
        const int col = n*16 + l15;
        br1v[n] = br1[col];
        wv0[n]  = wr2[col];
        wv1[n]  = wr2[64 + col];
        wv2[n]  = wr2[128 + col];
    }
    const float b2r0 = br2[0], b2r1 = br2[1], b2r2 = br2[2];

    #pragma unroll
    for (int reg = 0; reg < 4; ++reg){
        float r0 = 0.f, r1 = 0.f, r2 = 0.f;
        #pragma unroll
        for (int n = 0; n < 4; ++n){
            const float h = gelu_fast(acc[n][reg] + br1v[n]);
            r0 += h * wv0[n];
            r1 += h * wv1[n];
            r2 += h * wv2[n];
        }
        r0 += __shfl_xor(r0, 1); r0 += __shfl_xor(r0, 2); r0 += __shfl_xor(r0, 4); r0 += __shfl_xor(r0, 8);
        r1 += __shfl_xor(r1, 1); r1 += __shfl_xor(r1, 2); r1 += __shfl_xor(r1, 4); r1 += __shfl_xor(r1, 8);
        r2 += __shfl_xor(r2, 1); r2 += __shfl_xor(r2, 2); r2 += __shfl_xor(r2, 4); r2 += __shfl_xor(r2, 8);

        if (l15 == 0){
            const int row = rowbase + l4*4 + reg;
            const int b   = row >> 16;
            const int pix = row & 65535;
            out[((size_t)(b*3 + 0) << 16) + pix] = r0 + b2r0;
            out[((size_t)(b*3 + 1) << 16) + pix] = r1 + b2r1;
            out[((size_t)(b*3 + 2) << 16) + pix] = r2 + b2r2;
        }
    }
}

// ---------------------------------------------------------------------------
// Fallback monolithic kernel (round-1 proven; used only if ws too small)
// ---------------------------------------------------------------------------
__global__ __launch_bounds__(256) void main_kernel_mono(
    const float* __restrict__ feat,
    const float* __restrict__ wk1,
    const float* __restrict__ wk2, const float* __restrict__ bk2,
    const float* __restrict__ wr1, const float* __restrict__ br1,
    const float* __restrict__ wr2, const float* __restrict__ br2,
    const float* __restrict__ contrib,
    float* __restrict__ out)
{
    const int tid = blockIdx.x * 256 + threadIdx.x;
    const int b  = tid >> 16;
    const int qi = tid & 65535;
    const int oy = qi >> 8;
    const int ox = qi & 255;

    int cy = (oy - 1) >> 1; if (cy < 0) cy = 0;
    int cx = (ox - 1) >> 1; if (cx < 0) cx = 0;

    int ry[3], rx[3];
    #pragma unroll
    for (int k = 0; k < 3; ++k){ ry[k] = refl(cy-1+k, HH); rx[k] = refl(cx-1+k, WW); }

    const int p = ((oy & 1) << 1) | (ox & 1);
    const float* __restrict__ fb = feat + ((size_t)b << 20);

    float w9[9];
    #pragma unroll
    for (int k = 0; k < 9; ++k) w9[k] = bk2[k];

    for (int oc = 0; oc < 4; ++oc){
        float acc[32];
        #pragma unroll
        for (int j = 0; j < 32; ++j) acc[j] = contrib[p*128 + oc*32 + j];
        for (int c = 0; c < 64; ++c){
            const float* __restrict__ fc = fb + c * (HH*WW);
            float v[9];
            #pragma unroll
            for (int ky = 0; ky < 3; ++ky){
                const float* __restrict__ frow = fc + ry[ky] * WW;
                #pragma unroll
                for (int kx = 0; kx < 3; ++kx) v[ky*3 + kx] = frow[rx[kx]];
            }
            const float* __restrict__ wrow0 = wk1 + (oc*32) * 640 + c * 9;
            #pragma unroll
            for (int j = 0; j < 32; ++j){
                const float* __restrict__ wrow = wrow0 + j * 640;
                float a = acc[j];
                #pragma unroll
                for (int kk = 0; kk < 9; ++kk) a += v[kk] * wrow[kk];
                acc[j] = a;
            }
        }
        #pragma unroll
        for (int j = 0; j < 32; ++j){
            const float h = gelu_f(acc[j]);
            const int o = oc*32 + j;
            #pragma unroll
            for (int k = 0; k < 9; ++k) w9[k] += h * wk2[k*128 + o];
        }
    }

    float mx = w9[0];
    #pragma unroll
    for (int k = 1; k < 9; ++k) mx = fmaxf(mx, w9[k]);
    float sum = 0.0f;
    #pragma unroll
    for (int k = 0; k < 9; ++k){ w9[k] = expf(w9[k] - mx); sum += w9[k]; }
    const float inv = 1.0f / sum;
    #pragma unroll
    for (int k = 0; k < 9; ++k) w9[k] *= inv;

    float fq[64];
    #pragma unroll
    for (int c = 0; c < 64; ++c){
        float a = 0.0f;
        #pragma unroll
        for (int k = 0; k < 9; ++k){
            const int j  = k*64 + c;
            const int ch = j / 9;
            const int kk = j % 9;
            a += w9[k] * fb[ch*(HH*WW) + ry[kk/3]*WW + rx[kk%3]];
        }
        fq[c] = a;
    }

    float r0 = br2[0], r1 = br2[1], r2 = br2[2];
    for (int o = 0; o < 64; ++o){
        float a = br1[o];
        #pragma unroll
        for (int c = 0; c < 64; ++c) a += fq[c] * wr1[o*64 + c];
        const float h = gelu_f(a);
        r0 += h * wr2[o];
        r1 += h * wr2[64 + o];
        r2 += h * wr2[128 + o];
    }

    const int pix = (oy << 8) | ox;
    out[((size_t)(b*3 + 0) << 16) + pix] = r0;
    out[((size_t)(b*3 + 1) << 16) + pix] = r1;
    out[((size_t)(b*3 + 2) << 16) + pix] = r2;
}

extern "C" void kernel_launch(void* const* d_in, const int* in_sizes, int n_in,
                              void* d_out, int out_size, void* d_ws, size_t ws_size,
                              hipStream_t stream)
{
    const float* feat = (const float*)d_in[0];
    const float* w1m  = (const float*)d_in[1];
    const float* b1m  = (const float*)d_in[2];
    const float* w2m  = (const float*)d_in[3];
    const float* b2m  = (const float*)d_in[4];
    const float* wk1  = (const float*)d_in[5];
    const float* bk1  = (const float*)d_in[6];
    const float* wk2  = (const float*)d_in[7];
    const float* bk2  = (const float*)d_in[8];
    const float* wr1  = (const float*)d_in[9];
    const float* br1  = (const float*)d_in[10];
    const float* wr2  = (const float*)d_in[11];
    const float* br2  = (const float*)d_in[12];

    float* out = (float*)d_out;

    // ws layout (~21 MB):
    char* ws = (char*)d_ws;
    float*     contrib = (float*)ws;                       //       0 .. 2048
    ushort*    wk1tap  = (ushort*)(ws + 8192);             //    8192 .. 155648
    _Float16*  wr1h    = (_Float16*)(ws + 155648);         //  155648 .. 172032
    ushort*    featTp  = (ushort*)(ws + 172032);           //  172032 .. 4498432
    _Float16*  fqh     = (_Float16*)(ws + 4498432);        // 4498432 .. 21275648
    const size_t need = 21275648;

    hipLaunchKernelGGL(prep_all, dim3(321), dim3(256), 0, stream,
                       w1m, b1m, w2m, b2m, wk1, bk1, wr1, contrib, wk1tap, wr1h);

    if (ws_size >= need){
        hipLaunchKernelGGL(featTp_kernel, dim3(1057), dim3(256), 0, stream, feat, featTp);
        hipLaunchKernelGGL(conv_kernel, dim3(512), dim3(512), 0, stream,
                           featTp, wk1tap, wk2, bk2, contrib, fqh);
        hipLaunchKernelGGL(rgb_kernel, dim3(2048), dim3(256), 0, stream,
                           fqh, wr1h, br1, wr2, br2, out);
    } else {
        hipLaunchKernelGGL(main_kernel_mono, dim3(512), dim3(256), 0, stream,
                           feat, wk1, wk2, bk2, wr1, br1, wr2, br2, contrib, out);
    }
}

// Round 8
// 184.195 us; speedup vs baseline: 2.9499x; 1.0016x over previous
//
#include <hip/hip_runtime.h>
#include <math.h>

#define HH 128
#define WW 128

typedef __attribute__((ext_vector_type(8))) short s16x8;
typedef __attribute__((ext_vector_type(8))) _Float16 h16x8;
typedef __attribute__((ext_vector_type(4))) float f32x4;

__device__ __forceinline__ float gelu_f(float x){
    return 0.5f * x * (1.0f + erff(x * 0.70710678118654752440f));
}
// tanh-approx gelu with hardware rcp (no fp32 div). max err ~4e-4.
__device__ __forceinline__ float gelu2(float x){
    const float u2 = 1.5957691216057308f * x * (1.0f + 0.044715f * x * x);
    const float e  = __expf(u2);
    const float t  = 1.0f - 2.0f * __builtin_amdgcn_rcpf(e + 1.0f);
    return 0.5f * x * (1.0f + t);
}
__device__ __forceinline__ int refl(int v, int n){
    return v < 0 ? -v : (v >= n ? 2*n - 2 - v : v);
}
__device__ __forceinline__ ushort f2bf(float f){
    unsigned int b = __float_as_uint(f);
    unsigned int r = (b + 0x7FFFu + ((b >> 16) & 1u)) >> 16;
    return (ushort)r;
}
__device__ __forceinline__ float bf2f(ushort u){
    return __uint_as_float(((unsigned int)u) << 16);
}

// ---------------------------------------------------------------------------
// featTp_kernel v2: LDS-transposed. 260 blocks = (b, out-row). Coalesced row
// loads (lane = src col) -> ushort tile -> coalesced 16B channel-minor writes.
// featTp[b][row][col][c] = bf16(feat[b][c][refl(row-1)][refl(col-1)])
// ---------------------------------------------------------------------------
__global__ __launch_bounds__(256) void featTp_kernel(
    const float* __restrict__ feat, ushort* __restrict__ featTp)
{
    __shared__ ushort tile[64*132];

    const int blk = blockIdx.x;            // 0..259
    const int b   = blk / 130;
    const int row = blk - b*130;
    const int sr  = refl(row - 1, HH);

    const int c2   = threadIdx.x >> 7;     // 0/1
    const int scol = threadIdx.x & 127;    // src col

    #pragma unroll 4
    for (int cc = 0; cc < 32; ++cc){
        const int c = cc*2 + c2;
        const float v = feat[(((size_t)(b*64 + c)) << 14) + (sr << 7) + scol];
        const ushort bv = f2bf(v);
        tile[c*132 + scol + 1] = bv;              // out col = src col + 1
        if (scol == 1)   tile[c*132 + 0]   = bv;  // reflect left
        if (scol == 126) tile[c*132 + 129] = bv;  // reflect right
    }
    __syncthreads();

    for (int e = threadIdx.x; e < 1040; e += 256){
        const int col = e >> 3;            // 0..129
        const int cb  = e & 7;
        ushort tmp[8];
        #pragma unroll
        for (int j = 0; j < 8; ++j) tmp[j] = tile[(cb*8 + j)*132 + col];
        *(int4*)(featTp + ((((size_t)b*130 + row)*130 + col) << 6) + cb*8)
            = *(const int4*)tmp;
    }
}

// ---------------------------------------------------------------------------
// prep_all: 321 blocks.
//   block 0           : meta-MLP (parallel) -> contrib[4][128]
//   blocks 1..288     : wk1tap[tap][o][c] bf16
//   blocks 289..320   : wr1h[o][c] fp16
// ---------------------------------------------------------------------------
__global__ __launch_bounds__(256) void prep_all(
    const float* __restrict__ w1m, const float* __restrict__ b1m,
    const float* __restrict__ w2m, const float* __restrict__ b2m,
    const float* __restrict__ wk1, const float* __restrict__ bk1,
    const float* __restrict__ wr1,
    float* __restrict__ contrib, ushort* __restrict__ wk1tap,
    _Float16* __restrict__ wr1h)
{
    const int blk = blockIdx.x;
    const int t = threadIdx.x;

    if (blk == 0){
        __shared__ float hs[4][64];
        __shared__ float m_emb[4][64];
        const int p = t >> 6;
        const int j = t & 63;

        const float du = (p & 1) ? -0.25f : 0.25f;
        const float dv = (p >> 1) ? -0.25f : 0.25f;
        const float mv[5] = {2.0f, du, dv, 0.5f, 0.3f};

        float enc[85];
        #pragma unroll
        for (int f = 0; f < 5; ++f){
            enc[f*17] = mv[f];
            float fr = 3.14159265358979323846f;
            #pragma unroll
            for (int b = 0; b < 8; ++b){
                float xb = mv[f] * fr;
                enc[f*17 + 1 + b] = sinf(xb);
                enc[f*17 + 9 + b] = cosf(xb);
                fr *= 2.0f;
            }
        }

        float h = b1m[j];
        const float* __restrict__ wrow = w1m + j*85;
        #pragma unroll
        for (int i = 0; i < 85; ++i) h += enc[i] * wrow[i];
        hs[p][j] = gelu_f(h);
        __syncthreads();

        {
            const int o = j;
            float acc = b2m[o];
            const float* __restrict__ w2row = w2m + o*64;
            #pragma unroll
            for (int jj = 0; jj < 64; ++jj) acc += hs[p][jj] * w2row[jj];
            m_emb[p][o] = acc;
        }
        __syncthreads();

        for (int e = t; e < 512; e += 256){
            const int pp = e >> 7;
            const int oo = e & 127;
            float a = bk1[oo];
            #pragma unroll
            for (int jj = 0; jj < 64; ++jj) a += m_emb[pp][jj] * wk1[oo*640 + 576 + jj];
            contrib[e] = a;
        }
    } else if (blk <= 288){
        const int i = (blk - 1)*256 + t;      // 0..73727
        if (i < 73728){
            const int c   = i & 63;
            const int o   = (i >> 6) & 127;
            const int tap = i >> 13;
            wk1tap[i] = f2bf(wk1[o*640 + c*9 + tap]);
        }
    } else {
        const int i = (blk - 289)*256 + t;    // 0..8191
        if (i < 8192) wr1h[i] = (_Float16)wr1[i];
    }
}

// ---------------------------------------------------------------------------
// conv_kernel: MFMA conv (K=576) + w9 epilogue + fq gather. 512 blocks x 512.
// LDS 52.5KB -> 3 blocks/CU.  Phase 2: thread=(cell,p), lane=cell (conflict-
// free f16 Ls reads), rcp-gelu, in-register softmax.
// ---------------------------------------------------------------------------
__global__ __launch_bounds__(512) void conv_kernel(
    const ushort* __restrict__ featTp,
    const ushort* __restrict__ wk1tap,
    const float* __restrict__ wk2, const float* __restrict__ bk2,
    const float* __restrict__ contrib,
    _Float16* __restrict__ fqh)
{
    __shared__ ushort As[4*34*64];      // 17408 B  patch region (c-blk XOR swz)
    __shared__ ushort Ls16[64*130];     // 16640 B  logits f16, stride 130
    __shared__ float  wk2t[128*12];     //  6144 B  wk2 transposed [o][k]
    __shared__ float  w9s[256*10];      // 10240 B  softmaxed weights
    __shared__ float  contribs[512];    //  2048 B
                                        // total 52480 B -> 3 blocks/CU

    const int t   = threadIdx.x;
    const int blk = blockIdx.x;
    const int b   = blk >> 8;
    const int rem = blk & 255;
    const int cy0 = (rem >> 2) * 2;
    const int cx0 = (rem & 3) * 32;

    // ---- stage ----
    for (int e = t; e < 1088; e += 512){
        const int r   = e / 272;
        const int rm  = e - r * 272;
        const int col = rm >> 3;
        const int cb  = rm & 7;
        const ushort* src = featTp + ((((size_t)b*130 + cy0 + r)*130 + cx0 + col) << 6) + cb*8;
        const int didx = (r*34 + col)*64 + ((cb ^ (col & 7)) << 3);
        *(int4*)&As[didx] = *(const int4*)src;
    }
    for (int e = t; e < 1536; e += 512){
        const int o = (e * 10923) >> 17;   // e/12 for e<1536
        const int k = e - o*12;
        if (k < 9) wk2t[e] = wk2[k*128 + o];
    }
    if (t < 512) contribs[t] = contrib[t];
    __syncthreads();

    // ---- Phase 1: MFMA conv -> Ls16 (f16) ----
    {
        const int lane = t & 63;
        const int w    = t >> 6;
        const int wn   = w & 1;
        const int wq   = w >> 1;
        const int cellrow = wq >> 1;
        const int colblk  = (wq & 1) * 16;
        const int l15  = lane & 15;
        const int l4   = lane >> 4;

        f32x4 acc[4];
        #pragma unroll
        for (int n = 0; n < 4; ++n) acc[n] = (f32x4){0.f,0.f,0.f,0.f};

        const int acol = colblk + l15;

        #pragma unroll
        for (int tap = 0; tap < 9; ++tap){
            const int ky = tap / 3;
            const int kx = tap - ky * 3;

            s16x8 bf[2][4];
            #pragma unroll
            for (int ks = 0; ks < 2; ++ks)
                #pragma unroll
                for (int n = 0; n < 4; ++n)
                    bf[ks][n] = *(const s16x8*)(wk1tap +
                        (((size_t)tap << 13) + ((wn*64 + n*16 + l15) << 6) + ks*32 + l4*8));

            const int col = acol + kx;
            const int rowbase = (cellrow + ky)*34 + col;
            const int sw = (col & 7);
            #pragma unroll
            for (int ks = 0; ks < 2; ++ks){
                const int cb0 = ks*4 + l4;
                const s16x8 af = *(const s16x8*)&As[rowbase*64 + ((cb0 ^ sw) << 3)];
                #pragma unroll
                for (int n = 0; n < 4; ++n)
                    acc[n] = __builtin_amdgcn_mfma_f32_16x16x32_bf16(af, bf[ks][n], acc[n], 0, 0, 0);
            }
        }

        #pragma unroll
        for (int n = 0; n < 4; ++n){
            #pragma unroll
            for (int reg = 0; reg < 4; ++reg){
                const int lc = cellrow*32 + colblk + l4*4 + reg;
                const int o  = wn*64 + n*16 + l15;
                Ls16[lc*130 + o] = __builtin_bit_cast(ushort, (_Float16)acc[n][reg]);
            }
        }
    }
    __syncthreads();

    // ---- Phase 2: w9 = softmax(wk2 . gelu(L + contrib[p]) + bk2) ----
    if (t < 256){
        const int cell = t & 63;     // lane = cell -> conflict-free Ls reads
        const int p    = t >> 6;     // wave-uniform

        float w9[9];
        #pragma unroll
        for (int k = 0; k < 9; ++k) w9[k] = 0.0f;

        const float* __restrict__ cp = contribs + p*128;
        for (int o = 0; o < 128; ++o){
            const float lv = (float)__builtin_bit_cast(_Float16, Ls16[cell*130 + o]);
            const float h  = gelu2(lv + cp[o]);
            const f32x4 wa = *(const f32x4*)&wk2t[o*12];
            const f32x4 wb = *(const f32x4*)&wk2t[o*12 + 4];
            w9[0] += h*wa[0]; w9[1] += h*wa[1]; w9[2] += h*wa[2]; w9[3] += h*wa[3];
            w9[4] += h*wb[0]; w9[5] += h*wb[1]; w9[6] += h*wb[2]; w9[7] += h*wb[3];
            w9[8] += h*wk2t[o*12 + 8];
        }
        #pragma unroll
        for (int k = 0; k < 9; ++k) w9[k] += bk2[k];

        float mx = w9[0];
        #pragma unroll
        for (int k = 1; k < 9; ++k) mx = fmaxf(mx, w9[k]);
        float sum = 0.0f;
        #pragma unroll
        for (int k = 0; k < 9; ++k){ w9[k] = __expf(w9[k] - mx); sum += w9[k]; }
        const float inv = __builtin_amdgcn_rcpf(sum);
        #pragma unroll
        for (int k = 0; k < 9; ++k) w9s[t*10 + k] = w9[k] * inv;
    }
    __syncthreads();

    // ---- Phase 3: fq for 4 parities from As; write fqh (fp16) ----
    {
        const int ci  = t >> 3;          // cell 0..63
        const int sub = t & 7;           // channel block
        const int rr  = ci >> 5;
        const int x   = ci & 31;
        const int base_rc = rr*34 + x;
        const int c0 = sub*8;

        float w9r[4][9];
        #pragma unroll
        for (int p = 0; p < 4; ++p)
            #pragma unroll
            for (int k = 0; k < 9; ++k)
                w9r[p][k] = w9s[(p*64 + ci)*10 + k];

        float fqa[4][8];
        #pragma unroll
        for (int p = 0; p < 4; ++p)
            #pragma unroll
            for (int i = 0; i < 8; ++i) fqa[p][i] = 0.0f;

        #pragma unroll
        for (int k = 0; k < 9; ++k){
            #pragma unroll
            for (int i = 0; i < 8; ++i){
                const int e   = k*64 + c0 + i;
                const int ch  = (e * 7282) >> 16;     // e/9
                const int tap = e - 9*ch;
                const int ty  = (tap * 11) >> 5;      // tap/3
                const int tx  = tap - 3*ty;
                const int col = x + tx;
                const int aidx = ((base_rc + ty*34 + tx) << 6)
                               + (((ch >> 3) ^ (col & 7)) << 3) + (ch & 7);
                const float v = bf2f(As[aidx]);
                fqa[0][i] += w9r[0][k] * v;
                fqa[1][i] += w9r[1][k] * v;
                fqa[2][i] += w9r[2][k] * v;
                fqa[3][i] += w9r[3][k] * v;
            }
        }

        const int gy = cy0 + rr;
        const int gx = cx0 + x;

        #pragma unroll
        for (int p = 0; p < 4; ++p){
            const int py = p >> 1, px = p & 1;
            h16x8 hv;
            #pragma unroll
            for (int i = 0; i < 8; ++i) hv[i] = (_Float16)fqa[p][i];

            const int oy0 = 2*gy + 2 - py;
            const int ox0 = 2*gx + 2 - px;
            const bool y0ok = (py == 1) || (gy < 127);
            const bool x0ok = (px == 1) || (gx < 127);
            const bool yEx  = (gy == 0) && (py == 0);
            const bool xEx  = (gx == 0) && (px == 0);

            if (y0ok && x0ok)
                *(h16x8*)(fqh + (((size_t)((b << 16) | (oy0 << 8) | ox0)) << 6) + c0) = hv;
            if (y0ok && xEx)
                *(h16x8*)(fqh + (((size_t)((b << 16) | (oy0 << 8))) << 6) + c0) = hv;
            if (yEx && x0ok)
                *(h16x8*)(fqh + (((size_t)((b << 16) | ox0)) << 6) + c0) = hv;
            if (yEx && xEx)
                *(h16x8*)(fqh + (((size_t)(b << 16)) << 6) + c0) = hv;
        }
    }
}

// ---------------------------------------------------------------------------
// rgb_kernel: hidden = gelu(fq @ wr1^T + br1) via fp16 MFMA, layer2 via shfl.
// ---------------------------------------------------------------------------
__global__ __launch_bounds__(256) void rgb_kernel(
    const _Float16* __restrict__ fqh,
    const _Float16* __restrict__ wr1h,
    const float* __restrict__ br1, const float* __restrict__ wr2,
    const float* __restrict__ br2,
    float* __restrict__ out)
{
    const int t    = threadIdx.x;
    const int w    = t >> 6;
    const int lane = t & 63;
    const int l15  = lane & 15;
    const int l4   = lane >> 4;
    const int rowbase = blockIdx.x*64 + w*16;

    const h16x8 a0 = *(const h16x8*)&fqh[(size_t)(rowbase + l15)*64 + l4*8];
    const h16x8 a1 = *(const h16x8*)&fqh[(size_t)(rowbase + l15)*64 + 32 + l4*8];

    f32x4 acc[4];
    #pragma unroll
    for (int n = 0; n < 4; ++n){
        const h16x8 b0 = *(const h16x8*)&wr1h[(n*16 + l15)*64 + l4*8];
        const h16x8 b1 = *(const h16x8*)&wr1h[(n*16 + l15)*64 + 32 + l4*8];
        acc[n] = (f32x4){0.f,0.f,0.f,0.f};
        acc[n] = __builtin_amdgcn_mfma_f32_16x16x32_f16(a0, b0, acc[n], 0, 0, 0);
        acc[n] = __builtin_amdgcn_mfma_f32_16x16x32_f16(a1, b1, acc[n], 0, 0, 0);
    }

    f32x4 br1v, wv0, wv1, wv2;
    #pragma unroll
    for (int n = 0; n < 4; ++n){
        const int col = n*16 + l15;
        br1v[n] = br1[col];
        wv0[n]  = wr2[col];
        wv1[n]  = wr2[64 + col];
        wv2[n]  = wr2[128 + col];
    }
    const float b2r0 = br2[0], b2r1 = br2[1], b2r2 = br2[2];

    #pragma unroll
    for (int reg = 0; reg < 4; ++reg){
        float r0 = 0.f, r1 = 0.f, r2 = 0.f;
        #pragma unroll
        for (int n = 0; n < 4; ++n){
            const float h = gelu2(acc[n][reg] + br1v[n]);
            r0 += h * wv0[n];
            r1 += h * wv1[n];
            r2 += h * wv2[n];
        }
        r0 += __shfl_xor(r0, 1); r0 += __shfl_xor(r0, 2); r0 += __shfl_xor(r0, 4); r0 += __shfl_xor(r0, 8);
        r1 += __shfl_xor(r1, 1); r1 += __shfl_xor(r1, 2); r1 += __shfl_xor(r1, 4); r1 += __shfl_xor(r1, 8);
        r2 += __shfl_xor(r2, 1); r2 += __shfl_xor(r2, 2); r2 += __shfl_xor(r2, 4); r2 += __shfl_xor(r2, 8);

        if (l15 == 0){
            const int row = rowbase + l4*4 + reg;
            const int b   = row >> 16;
            const int pix = row & 65535;
            out[((size_t)(b*3 + 0) << 16) + pix] = r0 + b2r0;
            out[((size_t)(b*3 + 1) << 16) + pix] = r1 + b2r1;
            out[((size_t)(b*3 + 2) << 16) + pix] = r2 + b2r2;
        }
    }
}

// ---------------------------------------------------------------------------
// Fallback monolithic kernel (round-1 proven; used only if ws too small)
// ---------------------------------------------------------------------------
__global__ __launch_bounds__(256) void main_kernel_mono(
    const float* __restrict__ feat,
    const float* __restrict__ wk1,
    const float* __restrict__ wk2, const float* __restrict__ bk2,
    const float* __restrict__ wr1, const float* __restrict__ br1,
    const float* __restrict__ wr2, const float* __restrict__ br2,
    const float* __restrict__ contrib,
    float* __restrict__ out)
{
    const int tid = blockIdx.x * 256 + threadIdx.x;
    const int b  = tid >> 16;
    const int qi = tid & 65535;
    const int oy = qi >> 8;
    const int ox = qi & 255;

    int cy = (oy - 1) >> 1; if (cy < 0) cy = 0;
    int cx = (ox - 1) >> 1; if (cx < 0) cx = 0;

    int ry[3], rx[3];
    #pragma unroll
    for (int k = 0; k < 3; ++k){ ry[k] = refl(cy-1+k, HH); rx[k] = refl(cx-1+k, WW); }

    const int p = ((oy & 1) << 1) | (ox & 1);
    const float* __restrict__ fb = feat + ((size_t)b << 20);

    float w9[9];
    #pragma unroll
    for (int k = 0; k < 9; ++k) w9[k] = bk2[k];

    for (int oc = 0; oc < 4; ++oc){
        float acc[32];
        #pragma unroll
        for (int j = 0; j < 32; ++j) acc[j] = contrib[p*128 + oc*32 + j];
        for (int c = 0; c < 64; ++c){
            const float* __restrict__ fc = fb + c * (HH*WW);
            float v[9];
            #pragma unroll
            for (int ky = 0; ky < 3; ++ky){
                const float* __restrict__ frow = fc + ry[ky] * WW;
                #pragma unroll
                for (int kx = 0; kx < 3; ++kx) v[ky*3 + kx] = frow[rx[kx]];
            }
            const float* __restrict__ wrow0 = wk1 + (oc*32) * 640 + c * 9;
            #pragma unroll
            for (int j = 0; j < 32; ++j){
                const float* __restrict__ wrow = wrow0 + j * 640;
                float a = acc[j];
                #pragma unroll
                for (int kk = 0; kk < 9; ++kk) a += v[kk] * wrow[kk];
                acc[j] = a;
            }
        }
        #pragma unroll
        for (int j = 0; j < 32; ++j){
            const float h = gelu_f(acc[j]);
            const int o = oc*32 + j;
            #pragma unroll
            for (int k = 0; k < 9; ++k) w9[k] += h * wk2[k*128 + o];
        }
    }

    float mx = w9[0];
    #pragma unroll
    for (int k = 1; k < 9; ++k) mx = fmaxf(mx, w9[k]);
    float sum = 0.0f;
    #pragma unroll
    for (int k = 0; k < 9; ++k){ w9[k] = expf(w9[k] - mx); sum += w9[k]; }
    const float inv = 1.0f / sum;
    #pragma unroll
    for (int k = 0; k < 9; ++k) w9[k] *= inv;

    float fq[64];
    #pragma unroll
    for (int c = 0; c < 64; ++c){
        float a = 0.0f;
        #pragma unroll
        for (int k = 0; k < 9; ++k){
            const int j  = k*64 + c;
            const int ch = j / 9;
            const int kk = j % 9;
            a += w9[k] * fb[ch*(HH*WW) + ry[kk/3]*WW + rx[kk%3]];
        }
        fq[c] = a;
    }

    float r0 = br2[0], r1 = br2[1], r2 = br2[2];
    for (int o = 0; o < 64; ++o){
        float a = br1[o];
        #pragma unroll
        for (int c = 0; c < 64; ++c) a += fq[c] * wr1[o*64 + c];
        const float h = gelu_f(a);
        r0 += h * wr2[o];
        r1 += h * wr2[64 + o];
        r2 += h * wr2[128 + o];
    }

    const int pix = (oy << 8) | ox;
    out[((size_t)(b*3 + 0) << 16) + pix] = r0;
    out[((size_t)(b*3 + 1) << 16) + pix] = r1;
    out[((size_t)(b*3 + 2) << 16) + pix] = r2;
}

extern "C" void kernel_launch(void* const* d_in, const int* in_sizes, int n_in,
                              void* d_out, int out_size, void* d_ws, size_t ws_size,
                              hipStream_t stream)
{
    const float* feat = (const float*)d_in[0];
    const float* w1m  = (const float*)d_in[1];
    const float* b1m  = (const float*)d_in[2];
    const float* w2m  = (const float*)d_in[3];
    const float* b2m  = (const float*)d_in[4];
    const float* wk1  = (const float*)d_in[5];
    const float* bk1  = (const float*)d_in[6];
    const float* wk2  = (const float*)d_in[7];
    const float* bk2  = (const float*)d_in[8];
    const float* wr1  = (const float*)d_in[9];
    const float* br1  = (const float*)d_in[10];
    const float* wr2  = (const float*)d_in[11];
    const float* br2  = (const float*)d_in[12];

    float* out = (float*)d_out;

    // ws layout (~21 MB):
    char* ws = (char*)d_ws;
    float*     contrib = (float*)ws;                       //       0 .. 2048
    ushort*    wk1tap  = (ushort*)(ws + 8192);             //    8192 .. 155648
    _Float16*  wr1h    = (_Float16*)(ws + 155648);         //  155648 .. 172032
    ushort*    featTp  = (ushort*)(ws + 172032);           //  172032 .. 4498432
    _Float16*  fqh     = (_Float16*)(ws + 4498432);        // 4498432 .. 21275648
    const size_t need = 21275648;

    hipLaunchKernelGGL(prep_all, dim3(321), dim3(256), 0, stream,
                       w1m, b1m, w2m, b2m, wk1, bk1, wr1, contrib, wk1tap, wr1h);

    if (ws_size >= need){
        hipLaunchKernelGGL(featTp_kernel, dim3(260), dim3(256), 0, stream, feat, featTp);
        hipLaunchKernelGGL(conv_kernel, dim3(512), dim3(512), 0, stream,
                           featTp, wk1tap, wk2, bk2, contrib, fqh);
        hipLaunchKernelGGL(rgb_kernel, dim3(2048), dim3(256), 0, stream,
                           fqh, wr1h, br1, wr2, br2, out);
    } else {
        hipLaunchKernelGGL(main_kernel_mono, dim3(512), dim3(256), 0, stream,
                           feat, wk1, wk2, bk2, wr1, br1, wr2, br2, contrib, out);
    }
}

// Round 9
// 177.319 us; speedup vs baseline: 3.0642x; 1.0388x over previous
//
#include <hip/hip_runtime.h>
#include <math.h>

#define HH 128
#define WW 128

typedef __attribute__((ext_vector_type(8))) short s16x8;
typedef __attribute__((ext_vector_type(8))) _Float16 h16x8;
typedef __attribute__((ext_vector_type(4))) float f32x4;

__device__ __forceinline__ float gelu_f(float x){
    return 0.5f * x * (1.0f + erff(x * 0.70710678118654752440f));
}
// tanh-approx gelu with hardware rcp (no fp32 div). max err ~4e-4.
__device__ __forceinline__ float gelu2(float x){
    const float u2 = 1.5957691216057308f * x * (1.0f + 0.044715f * x * x);
    const float e  = __expf(u2);
    const float t  = 1.0f - 2.0f * __builtin_amdgcn_rcpf(e + 1.0f);
    return 0.5f * x * (1.0f + t);
}
__device__ __forceinline__ int refl(int v, int n){
    return v < 0 ? -v : (v >= n ? 2*n - 2 - v : v);
}
__device__ __forceinline__ ushort f2bf(float f){
    unsigned int b = __float_as_uint(f);
    unsigned int r = (b + 0x7FFFu + ((b >> 16) & 1u)) >> 16;
    return (ushort)r;
}
__device__ __forceinline__ float bf2f(ushort u){
    return __uint_as_float(((unsigned int)u) << 16);
}

// ---------------------------------------------------------------------------
// prep_all: 581 blocks.
//   block 0       : meta-MLP (parallel) -> contrib[4][128]
//   1..288        : wk1tap[tap][o][c] bf16
//   289..320      : wr1h[o][c] fp16
//   321..580      : featTp rows (fused featTp_kernel: one (b,row) per block)
// ---------------------------------------------------------------------------
__global__ __launch_bounds__(256) void prep_all(
    const float* __restrict__ w1m, const float* __restrict__ b1m,
    const float* __restrict__ w2m, const float* __restrict__ b2m,
    const float* __restrict__ wk1, const float* __restrict__ bk1,
    const float* __restrict__ wr1, const float* __restrict__ feat,
    float* __restrict__ contrib, ushort* __restrict__ wk1tap,
    _Float16* __restrict__ wr1h, ushort* __restrict__ featTp)
{
    __shared__ ushort tile[64*132];    // used by featTp branch only
    const int blk = blockIdx.x;
    const int t = threadIdx.x;

    if (blk == 0){
        __shared__ float hs[4][64];
        __shared__ float m_emb[4][64];
        const int p = t >> 6;
        const int j = t & 63;

        const float du = (p & 1) ? -0.25f : 0.25f;
        const float dv = (p >> 1) ? -0.25f : 0.25f;
        const float mv[5] = {2.0f, du, dv, 0.5f, 0.3f};

        float enc[85];
        #pragma unroll
        for (int f = 0; f < 5; ++f){
            enc[f*17] = mv[f];
            float fr = 3.14159265358979323846f;
            #pragma unroll
            for (int b = 0; b < 8; ++b){
                float xb = mv[f] * fr;
                enc[f*17 + 1 + b] = sinf(xb);
                enc[f*17 + 9 + b] = cosf(xb);
                fr *= 2.0f;
            }
        }

        float h = b1m[j];
        const float* __restrict__ wrow = w1m + j*85;
        #pragma unroll
        for (int i = 0; i < 85; ++i) h += enc[i] * wrow[i];
        hs[p][j] = gelu_f(h);
        __syncthreads();

        {
            const int o = j;
            float acc = b2m[o];
            const float* __restrict__ w2row = w2m + o*64;
            #pragma unroll
            for (int jj = 0; jj < 64; ++jj) acc += hs[p][jj] * w2row[jj];
            m_emb[p][o] = acc;
        }
        __syncthreads();

        for (int e = t; e < 512; e += 256){
            const int pp = e >> 7;
            const int oo = e & 127;
            float a = bk1[oo];
            #pragma unroll
            for (int jj = 0; jj < 64; ++jj) a += m_emb[pp][jj] * wk1[oo*640 + 576 + jj];
            contrib[e] = a;
        }
    } else if (blk <= 288){
        const int i = (blk - 1)*256 + t;      // 0..73727
        if (i < 73728){
            const int c   = i & 63;
            const int o   = (i >> 6) & 127;
            const int tap = i >> 13;
            wk1tap[i] = f2bf(wk1[o*640 + c*9 + tap]);
        }
    } else if (blk <= 320){
        const int i = (blk - 289)*256 + t;    // 0..8191
        if (i < 8192) wr1h[i] = (_Float16)wr1[i];
    } else {
        // featTp: one (b,row) per block; LDS transpose for coalesced writes
        const int rb  = blk - 321;            // 0..259
        const int b   = rb / 130;
        const int row = rb - b*130;
        const int sr  = refl(row - 1, HH);

        const int c2   = t >> 7;              // 0/1
        const int scol = t & 127;

        #pragma unroll 4
        for (int cc = 0; cc < 32; ++cc){
            const int c = cc*2 + c2;
            const float v = feat[(((size_t)(b*64 + c)) << 14) + (sr << 7) + scol];
            const ushort bv = f2bf(v);
            tile[c*132 + scol + 1] = bv;
            if (scol == 1)   tile[c*132 + 0]   = bv;
            if (scol == 126) tile[c*132 + 129] = bv;
        }
        __syncthreads();

        for (int e = t; e < 1040; e += 256){
            const int col = e >> 3;
            const int cb  = e & 7;
            ushort tmp[8];
            #pragma unroll
            for (int j = 0; j < 8; ++j) tmp[j] = tile[(cb*8 + j)*132 + col];
            *(int4*)(featTp + ((((size_t)b*130 + row)*130 + col) << 6) + cb*8)
                = *(const int4*)tmp;
        }
    }
}

// ---------------------------------------------------------------------------
// conv_kernel: MFMA conv (K=576) + w9 epilogue + fq gather.
// 1024 blocks x 512 threads. Tile: 32 cells (2 rows x 16 cx) x 128 outs.
// LDS ~30.8KB -> 4 blocks/CU resident (grid-limited).
// Phase 2 uses ALL 512 threads: 4 threads per (cell,p) task, 32-o slice each,
// converged shfl_xor combine.
// ---------------------------------------------------------------------------
__global__ __launch_bounds__(512) void conv_kernel(
    const ushort* __restrict__ featTp,
    const ushort* __restrict__ wk1tap,
    const float* __restrict__ wk2, const float* __restrict__ bk2,
    const float* __restrict__ contrib,
    _Float16* __restrict__ fqh)
{
    __shared__ ushort As[4*18*64];      //  9216 B  patch region (c-blk XOR swz)
    __shared__ ushort Ls16[32*130];     //  8320 B  logits f16
    __shared__ float  wk2t[128*12];     //  6144 B  wk2 transposed [o][k]
    __shared__ float  w9s[128*10];      //  5120 B
    __shared__ float  contribs[512];    //  2048 B   (total 30848 B)

    const int t   = threadIdx.x;
    const int blk = blockIdx.x;
    const int b   = blk >> 9;
    const int rem = blk & 511;
    const int cy0 = (rem >> 3) * 2;          // cell row base (0..126)
    const int cx0 = (rem & 7) * 16;          // cell col base (0..112)

    // ---- stage As: rows cy0..cy0+3, cols cx0..cx0+17 ----
    for (int e = t; e < 576; e += 512){
        const int r   = e / 144;
        const int rm  = e - r * 144;
        const int col = rm >> 3;
        const int cb  = rm & 7;
        const ushort* src = featTp + ((((size_t)b*130 + cy0 + r)*130 + cx0 + col) << 6) + cb*8;
        const int didx = (r*18 + col)*64 + ((cb ^ (col & 7)) << 3);
        *(int4*)&As[didx] = *(const int4*)src;
    }
    for (int e = t; e < 1536; e += 512){
        const int o = (e * 10923) >> 17;   // e/12
        const int k = e - o*12;
        if (k < 9) wk2t[e] = wk2[k*128 + o];
    }
    if (t < 512) contribs[t] = contrib[t];
    __syncthreads();

    // ---- Phase 1: MFMA conv -> Ls16 (f16) ----
    {
        const int lane = t & 63;
        const int w    = t >> 6;
        const int wn   = w & 3;              // o quarter (32 each)
        const int cellrow = w >> 2;          // 0/1
        const int l15  = lane & 15;
        const int l4   = lane >> 4;

        f32x4 acc[2];
        acc[0] = (f32x4){0.f,0.f,0.f,0.f};
        acc[1] = (f32x4){0.f,0.f,0.f,0.f};

        #pragma unroll
        for (int tap = 0; tap < 9; ++tap){
            const int ky = tap / 3;
            const int kx = tap - ky * 3;

            s16x8 bf[2][2];
            #pragma unroll
            for (int ks = 0; ks < 2; ++ks)
                #pragma unroll
                for (int n = 0; n < 2; ++n)
                    bf[ks][n] = *(const s16x8*)(wk1tap +
                        (((size_t)tap << 13) + ((wn*32 + n*16 + l15) << 6) + ks*32 + l4*8));

            const int col = l15 + kx;
            const int rowbase = (cellrow + ky)*18 + col;
            const int sw = (col & 7);
            #pragma unroll
            for (int ks = 0; ks < 2; ++ks){
                const int cb0 = ks*4 + l4;
                const s16x8 af = *(const s16x8*)&As[rowbase*64 + ((cb0 ^ sw) << 3)];
                #pragma unroll
                for (int n = 0; n < 2; ++n)
                    acc[n] = __builtin_amdgcn_mfma_f32_16x16x32_bf16(af, bf[ks][n], acc[n], 0, 0, 0);
            }
        }

        #pragma unroll
        for (int n = 0; n < 2; ++n){
            #pragma unroll
            for (int reg = 0; reg < 4; ++reg){
                const int cell = cellrow*16 + l4*4 + reg;     // 0..31
                const int o    = wn*32 + n*16 + l15;
                Ls16[cell*130 + o] = __builtin_bit_cast(ushort, (_Float16)acc[n][reg]);
            }
        }
    }
    __syncthreads();

    // ---- Phase 2: w9 = softmax(wk2 . gelu(L + contrib[p]) + bk2), all 512 thr ----
    {
        const int q    = t & 3;          // o-slice
        const int task = t >> 2;         // 0..127
        const int cell = task & 31;
        const int p    = task >> 5;      // wave-uniform

        float w9[9];
        #pragma unroll
        for (int k = 0; k < 9; ++k) w9[k] = 0.0f;

        const float* __restrict__ cp = contribs + p*128 + q*32;
        const ushort* __restrict__ lp = &Ls16[cell*130 + q*32];
        for (int i = 0; i < 32; ++i){
            const float lv = (float)__builtin_bit_cast(_Float16, lp[i]);
            const float h  = gelu2(lv + cp[i]);
            const int o = q*32 + i;
            const f32x4 wa = *(const f32x4*)&wk2t[o*12];
            const f32x4 wb = *(const f32x4*)&wk2t[o*12 + 4];
            w9[0] += h*wa[0]; w9[1] += h*wa[1]; w9[2] += h*wa[2]; w9[3] += h*wa[3];
            w9[4] += h*wb[0]; w9[5] += h*wb[1]; w9[6] += h*wb[2]; w9[7] += h*wb[3];
            w9[8] += h*wk2t[o*12 + 8];
        }
        // converged 4-lane combine
        #pragma unroll
        for (int k = 0; k < 9; ++k){
            w9[k] += __shfl_xor(w9[k], 1);
            w9[k] += __shfl_xor(w9[k], 2);
            w9[k] += bk2[k];
        }

        float mx = w9[0];
        #pragma unroll
        for (int k = 1; k < 9; ++k) mx = fmaxf(mx, w9[k]);
        float sum = 0.0f;
        #pragma unroll
        for (int k = 0; k < 9; ++k){ w9[k] = __expf(w9[k] - mx); sum += w9[k]; }
        const float inv = __builtin_amdgcn_rcpf(sum);
        #pragma unroll
        for (int k = 0; k < 9; ++k)
            if ((k & 3) == q) w9s[task*10 + k] = w9[k] * inv;
    }
    __syncthreads();

    // ---- Phase 3: fq for 4 parities from As; write fqh (fp16) ----
    {
        const int ci  = t >> 4;          // cell 0..31
        const int sub = t & 15;          // channel block (4 ch each)
        const int rr  = ci >> 4;         // cell row in block (0/1)
        const int x   = ci & 15;         // cell col in block
        const int base_rc = rr*18 + x;
        const int c0 = sub*4;

        float w9r[4][9];
        #pragma unroll
        for (int p = 0; p < 4; ++p)
            #pragma unroll
            for (int k = 0; k < 9; ++k)
                w9r[p][k] = w9s[(p*32 + ci)*10 + k];

        float fqa[4][4];
        #pragma unroll
        for (int p = 0; p < 4; ++p)
            #pragma unroll
            for (int i = 0; i < 4; ++i) fqa[p][i] = 0.0f;

        #pragma unroll
        for (int k = 0; k < 9; ++k){
            #pragma unroll
            for (int i = 0; i < 4; ++i){
                const int e   = k*64 + c0 + i;
                const int ch  = (e * 7282) >> 16;     // e/9
                const int tap = e - 9*ch;
                const int ty  = (tap * 11) >> 5;      // tap/3
                const int tx  = tap - 3*ty;
                const int col = x + tx;
                const int aidx = ((base_rc + ty*18 + tx) << 6)
                               + (((ch >> 3) ^ (col & 7)) << 3) + (ch & 7);
                const float v = bf2f(As[aidx]);
                fqa[0][i] += w9r[0][k] * v;
                fqa[1][i] += w9r[1][k] * v;
                fqa[2][i] += w9r[2][k] * v;
                fqa[3][i] += w9r[3][k] * v;
            }
        }

        const int gy = cy0 + rr;
        const int gx = cx0 + x;

        #pragma unroll
        for (int p = 0; p < 4; ++p){
            const int py = p >> 1, px = p & 1;
            short4 hv;
            hv.x = __builtin_bit_cast(short, (_Float16)fqa[p][0]);
            hv.y = __builtin_bit_cast(short, (_Float16)fqa[p][1]);
            hv.z = __builtin_bit_cast(short, (_Float16)fqa[p][2]);
            hv.w = __builtin_bit_cast(short, (_Float16)fqa[p][3]);

            const int oy0 = 2*gy + 2 - py;
            const int ox0 = 2*gx + 2 - px;
            const bool y0ok = (py == 1) || (gy < 127);
            const bool x0ok = (px == 1) || (gx < 127);
            const bool yEx  = (gy == 0) && (py == 0);
            const bool xEx  = (gx == 0) && (px == 0);

            if (y0ok && x0ok)
                *(short4*)(fqh + (((size_t)((b << 16) | (oy0 << 8) | ox0)) << 6) + c0) = hv;
            if (y0ok && xEx)
                *(short4*)(fqh + (((size_t)((b << 16) | (oy0 << 8))) << 6) + c0) = hv;
            if (yEx && x0ok)
                *(short4*)(fqh + (((size_t)((b << 16) | ox0)) << 6) + c0) = hv;
            if (yEx && xEx)
                *(short4*)(fqh + (((size_t)(b << 16)) << 6) + c0) = hv;
        }
    }
}

// ---------------------------------------------------------------------------
// rgb_kernel: hidden = gelu(fq @ wr1^T + br1) via fp16 MFMA, layer2 via shfl.
// ---------------------------------------------------------------------------
__global__ __launch_bounds__(256) void rgb_kernel(
    const _Float16* __restrict__ fqh,
    const _Float16* __restrict__ wr1h,
    const float* __restrict__ br1, const float* __restrict__ wr2,
    const float* __restrict__ br2,
    float* __restrict__ out)
{
    const int t    = threadIdx.x;
    const int w    = t >> 6;
    const int lane = t & 63;
    const int l15  = lane & 15;
    const int l4   = lane >> 4;
    const int rowbase = blockIdx.x*64 + w*16;

    const h16x8 a0 = *(const h16x8*)&fqh[(size_t)(rowbase + l15)*64 + l4*8];
    const h16x8 a1 = *(const h16x8*)&fqh[(size_t)(rowbase + l15)*64 + 32 + l4*8];

    f32x4 acc[4];
    #pragma unroll
    for (int n = 0; n < 4; ++n){
        const h16x8 b0 = *(const h16x8*)&wr1h[(n*16 + l15)*64 + l4*8];
        const h16x8 b1 = *(const h16x8*)&wr1h[(n*16 + l15)*64 + 32 + l4*8];
        acc[n] = (f32x4){0.f,0.f,0.f,0.f};
        acc[n] = __builtin_amdgcn_mfma_f32_16x16x32_f16(a0, b0, acc[n], 0, 0, 0);
        acc[n] = __builtin_amdgcn_mfma_f32_16x16x32_f16(a1, b1, acc[n], 0, 0, 0);
    }

    f32x4 br1v, wv0, wv1, wv2;
    #pragma unroll
    for (int n = 0; n < 4; ++n){
        const int col = n*16 + l15;
        br1v[n] = br1[col];
        wv0[n]  = wr2[col];
        wv1[n]  = wr2[64 + col];
        wv2[n]  = wr2[128 + col];
    }
    const float b2r0 = br2[0], b2r1 = br2[1], b2r2 = br2[2];

    #pragma unroll
    for (int reg = 0; reg < 4; ++reg){
        float r0 = 0.f, r1 = 0.f, r2 = 0.f;
        #pragma unroll
        for (int n = 0; n < 4; ++n){
            const float h = gelu2(acc[n][reg] + br1v[n]);
            r0 += h * wv0[n];
            r1 += h * wv1[n];
            r2 += h * wv2[n];
        }
        r0 += __shfl_xor(r0, 1); r0 += __shfl_xor(r0, 2); r0 += __shfl_xor(r0, 4); r0 += __shfl_xor(r0, 8);
        r1 += __shfl_xor(r1, 1); r1 += __shfl_xor(r1, 2); r1 += __shfl_xor(r1, 4); r1 += __shfl_xor(r1, 8);
        r2 += __shfl_xor(r2, 1); r2 += __shfl_xor(r2, 2); r2 += __shfl_xor(r2, 4); r2 += __shfl_xor(r2, 8);

        if (l15 == 0){
            const int row = rowbase + l4*4 + reg;
            const int b   = row >> 16;
            const int pix = row & 65535;
            out[((size_t)(b*3 + 0) << 16) + pix] = r0 + b2r0;
            out[((size_t)(b*3 + 1) << 16) + pix] = r1 + b2r1;
            out[((size_t)(b*3 + 2) << 16) + pix] = r2 + b2r2;
        }
    }
}

// ---------------------------------------------------------------------------
// Fallback monolithic kernel (round-1 proven; used only if ws too small)
// ---------------------------------------------------------------------------
__global__ __launch_bounds__(256) void main_kernel_mono(
    const float* __restrict__ feat,
    const float* __restrict__ wk1,
    const float* __restrict__ wk2, const float* __restrict__ bk2,
    const float* __restrict__ wr1, const float* __restrict__ br1,
    const float* __restrict__ wr2, const float* __restrict__ br2,
    const float* __restrict__ contrib,
    float* __restrict__ out)
{
    const int tid = blockIdx.x * 256 + threadIdx.x;
    const int b  = tid >> 16;
    const int qi = tid & 65535;
    const int oy = qi >> 8;
    const int ox = qi & 255;

    int cy = (oy - 1) >> 1; if (cy < 0) cy = 0;
    int cx = (ox - 1) >> 1; if (cx < 0) cx = 0;

    int ry[3], rx[3];
    #pragma unroll
    for (int k = 0; k < 3; ++k){ ry[k] = refl(cy-1+k, HH); rx[k] = refl(cx-1+k, WW); }

    const int p = ((oy & 1) << 1) | (ox & 1);
    const float* __restrict__ fb = feat + ((size_t)b << 20);

    float w9[9];
    #pragma unroll
    for (int k = 0; k < 9; ++k) w9[k] = bk2[k];

    for (int oc = 0; oc < 4; ++oc){
        float acc[32];
        #pragma unroll
        for (int j = 0; j < 32; ++j) acc[j] = contrib[p*128 + oc*32 + j];
        for (int c = 0; c < 64; ++c){
            const float* __restrict__ fc = fb + c * (HH*WW);
            float v[9];
            #pragma unroll
            for (int ky = 0; ky < 3; ++ky){
                const float* __restrict__ frow = fc + ry[ky] * WW;
                #pragma unroll
                for (int kx = 0; kx < 3; ++kx) v[ky*3 + kx] = frow[rx[kx]];
            }
            const float* __restrict__ wrow0 = wk1 + (oc*32) * 640 + c * 9;
            #pragma unroll
            for (int j = 0; j < 32; ++j){
                const float* __restrict__ wrow = wrow0 + j * 640;
                float a = acc[j];
                #pragma unroll
                for (int kk = 0; kk < 9; ++kk) a += v[kk] * wrow[kk];
                acc[j] = a;
            }
        }
        #pragma unroll
        for (int j = 0; j < 32; ++j){
            const float h = gelu_f(acc[j]);
            const int o = oc*32 + j;
            #pragma unroll
            for (int k = 0; k < 9; ++k) w9[k] += h * wk2[k*128 + o];
        }
    }

    float mx = w9[0];
    #pragma unroll
    for (int k = 1; k < 9; ++k) mx = fmaxf(mx, w9[k]);
    float sum = 0.0f;
    #pragma unroll
    for (int k = 0; k < 9; ++k){ w9[k] = expf(w9[k] - mx); sum += w9[k]; }
    const float inv = 1.0f / sum;
    #pragma unroll
    for (int k = 0; k < 9; ++k) w9[k] *= inv;

    float fq[64];
    #pragma unroll
    for (int c = 0; c < 64; ++c){
        float a = 0.0f;
        #pragma unroll
        for (int k = 0; k < 9; ++k){
            const int j  = k*64 + c;
            const int ch = j / 9;
            const int kk = j % 9;
            a += w9[k] * fb[ch*(HH*WW) + ry[kk/3]*WW + rx[kk%3]];
        }
        fq[c] = a;
    }

    float r0 = br2[0], r1 = br2[1], r2 = br2[2];
    for (int o = 0; o < 64; ++o){
        float a = br1[o];
        #pragma unroll
        for (int c = 0; c < 64; ++c) a += fq[c] * wr1[o*64 + c];
        const float h = gelu_f(a);
        r0 += h * wr2[o];
        r1 += h * wr2[64 + o];
        r2 += h * wr2[128 + o];
    }

    const int pix = (oy << 8) | ox;
    out[((size_t)(b*3 + 0) << 16) + pix] = r0;
    out[((size_t)(b*3 + 1) << 16) + pix] = r1;
    out[((size_t)(b*3 + 2) << 16) + pix] = r2;
}

extern "C" void kernel_launch(void* const* d_in, const int* in_sizes, int n_in,
                              void* d_out, int out_size, void* d_ws, size_t ws_size,
                              hipStream_t stream)
{
    const float* feat = (const float*)d_in[0];
    const float* w1m  = (const float*)d_in[1];
    const float* b1m  = (const float*)d_in[2];
    const float* w2m  = (const float*)d_in[3];
    const float* b2m  = (const float*)d_in[4];
    const float* wk1  = (const float*)d_in[5];
    const float* bk1  = (const float*)d_in[6];
    const float* wk2  = (const float*)d_in[7];
    const float* bk2  = (const float*)d_in[8];
    const float* wr1  = (const float*)d_in[9];
    const float* br1  = (const float*)d_in[10];
    const float* wr2  = (const float*)d_in[11];
    const float* br2  = (const float*)d_in[12];

    float* out = (float*)d_out;

    // ws layout (~21 MB):
    char* ws = (char*)d_ws;
    float*     contrib = (float*)ws;                       //       0 .. 2048
    ushort*    wk1tap  = (ushort*)(ws + 8192);             //    8192 .. 155648
    _Float16*  wr1h    = (_Float16*)(ws + 155648);         //  155648 .. 172032
    ushort*    featTp  = (ushort*)(ws + 172032);           //  172032 .. 4498432
    _Float16*  fqh     = (_Float16*)(ws + 4498432);        // 4498432 .. 21275648
    const size_t need = 21275648;

    if (ws_size >= need){
        hipLaunchKernelGGL(prep_all, dim3(581), dim3(256), 0, stream,
                           w1m, b1m, w2m, b2m, wk1, bk1, wr1, feat,
                           contrib, wk1tap, wr1h, featTp);
        hipLaunchKernelGGL(conv_kernel, dim3(1024), dim3(512), 0, stream,
                           featTp, wk1tap, wk2, bk2, contrib, fqh);
        hipLaunchKernelGGL(rgb_kernel, dim3(2048), dim3(256), 0, stream,
                           fqh, wr1h, br1, wr2, br2, out);
    } else {
        hipLaunchKernelGGL(prep_all, dim3(321), dim3(256), 0, stream,
                           w1m, b1m, w2m, b2m, wk1, bk1, wr1, feat,
                           contrib, wk1tap, wr1h, featTp);
        hipLaunchKernelGGL(main_kernel_mono, dim3(512), dim3(256), 0, stream,
                           feat, wk1, wk2, bk2, wr1, br1, wr2, br2, contrib, out);
    }
}

// Round 10
// 176.045 us; speedup vs baseline: 3.0864x; 1.0072x over previous
//
#include <hip/hip_runtime.h>
#include <math.h>

#define HH 128
#define WW 128

typedef __attribute__((ext_vector_type(8))) short s16x8;
typedef __attribute__((ext_vector_type(8))) _Float16 h16x8;
typedef __attribute__((ext_vector_type(4))) float f32x4;

__device__ __forceinline__ float gelu_f(float x){
    return 0.5f * x * (1.0f + erff(x * 0.70710678118654752440f));
}
// tanh-approx gelu with hardware rcp (no fp32 div). max err ~4e-4.
__device__ __forceinline__ float gelu2(float x){
    const float u2 = 1.5957691216057308f * x * (1.0f + 0.044715f * x * x);
    const float e  = __expf(u2);
    const float t  = 1.0f - 2.0f * __builtin_amdgcn_rcpf(e + 1.0f);
    return 0.5f * x * (1.0f + t);
}
__device__ __forceinline__ int refl(int v, int n){
    return v < 0 ? -v : (v >= n ? 2*n - 2 - v : v);
}
__device__ __forceinline__ ushort f2bf(float f){
    unsigned int b = __float_as_uint(f);
    unsigned int r = (b + 0x7FFFu + ((b >> 16) & 1u)) >> 16;
    return (ushort)r;
}
__device__ __forceinline__ float bf2f(ushort u){
    return __uint_as_float(((unsigned int)u) << 16);
}

// ---------------------------------------------------------------------------
// prep_all: 581 blocks.
//   block 0       : meta-MLP (parallel) -> contrib[4][128]
//   1..288        : wk1tap[tap][o][c] bf16
//   289..320      : wr1h[o][c] fp16
//   321..580      : featTp rows (one (b,row) per block, LDS transpose)
// ---------------------------------------------------------------------------
__global__ __launch_bounds__(256) void prep_all(
    const float* __restrict__ w1m, const float* __restrict__ b1m,
    const float* __restrict__ w2m, const float* __restrict__ b2m,
    const float* __restrict__ wk1, const float* __restrict__ bk1,
    const float* __restrict__ wr1, const float* __restrict__ feat,
    float* __restrict__ contrib, ushort* __restrict__ wk1tap,
    _Float16* __restrict__ wr1h, ushort* __restrict__ featTp)
{
    __shared__ ushort tile[64*132];
    const int blk = blockIdx.x;
    const int t = threadIdx.x;

    if (blk == 0){
        __shared__ float hs[4][64];
        __shared__ float m_emb[4][64];
        const int p = t >> 6;
        const int j = t & 63;

        const float du = (p & 1) ? -0.25f : 0.25f;
        const float dv = (p >> 1) ? -0.25f : 0.25f;
        const float mv[5] = {2.0f, du, dv, 0.5f, 0.3f};

        float enc[85];
        #pragma unroll
        for (int f = 0; f < 5; ++f){
            enc[f*17] = mv[f];
            float fr = 3.14159265358979323846f;
            #pragma unroll
            for (int b = 0; b < 8; ++b){
                float xb = mv[f] * fr;
                enc[f*17 + 1 + b] = sinf(xb);
                enc[f*17 + 9 + b] = cosf(xb);
                fr *= 2.0f;
            }
        }

        float h = b1m[j];
        const float* __restrict__ wrow = w1m + j*85;
        #pragma unroll
        for (int i = 0; i < 85; ++i) h += enc[i] * wrow[i];
        hs[p][j] = gelu_f(h);
        __syncthreads();

        {
            const int o = j;
            float acc = b2m[o];
            const float* __restrict__ w2row = w2m + o*64;
            #pragma unroll
            for (int jj = 0; jj < 64; ++jj) acc += hs[p][jj] * w2row[jj];
            m_emb[p][o] = acc;
        }
        __syncthreads();

        for (int e = t; e < 512; e += 256){
            const int pp = e >> 7;
            const int oo = e & 127;
            float a = bk1[oo];
            #pragma unroll
            for (int jj = 0; jj < 64; ++jj) a += m_emb[pp][jj] * wk1[oo*640 + 576 + jj];
            contrib[e] = a;
        }
    } else if (blk <= 288){
        const int i = (blk - 1)*256 + t;
        if (i < 73728){
            const int c   = i & 63;
            const int o   = (i >> 6) & 127;
            const int tap = i >> 13;
            wk1tap[i] = f2bf(wk1[o*640 + c*9 + tap]);
        }
    } else if (blk <= 320){
        const int i = (blk - 289)*256 + t;
        if (i < 8192) wr1h[i] = (_Float16)wr1[i];
    } else {
        const int rb  = blk - 321;            // 0..259
        const int b   = rb / 130;
        const int row = rb - b*130;
        const int sr  = refl(row - 1, HH);

        const int c2   = t >> 7;
        const int scol = t & 127;

        #pragma unroll 4
        for (int cc = 0; cc < 32; ++cc){
            const int c = cc*2 + c2;
            const float v = feat[(((size_t)(b*64 + c)) << 14) + (sr << 7) + scol];
            const ushort bv = f2bf(v);
            tile[c*132 + scol + 1] = bv;
            if (scol == 1)   tile[c*132 + 0]   = bv;
            if (scol == 126) tile[c*132 + 129] = bv;
        }
        __syncthreads();

        for (int e = t; e < 1040; e += 256){
            const int col = e >> 3;
            const int cb  = e & 7;
            ushort tmp[8];
            #pragma unroll
            for (int j = 0; j < 8; ++j) tmp[j] = tile[(cb*8 + j)*132 + col];
            *(int4*)(featTp + ((((size_t)b*130 + row)*130 + col) << 6) + cb*8)
                = *(const int4*)tmp;
        }
    }
}

// ---------------------------------------------------------------------------
// conv_fused: MFMA conv (K=576) + w9 + fq + RGB MLP, one kernel, direct out.
// 512 blocks x 512 threads. Tile: 64 cells (2 rows x 32 cx) -> 256 pixels.
// LDS: As 17408 | w9s 10240 | union{Ls16+wk2t+contribs (ph1-2) / fqs (ph3-4)}
//      = 62464 B -> 2 blocks/CU.
// ---------------------------------------------------------------------------
__global__ __launch_bounds__(512) void conv_fused(
    const ushort* __restrict__ featTp,
    const ushort* __restrict__ wk1tap,
    const float* __restrict__ wk2, const float* __restrict__ bk2,
    const float* __restrict__ contrib,
    const _Float16* __restrict__ wr1h,
    const float* __restrict__ br1, const float* __restrict__ wr2,
    const float* __restrict__ br2,
    float* __restrict__ out)
{
    __shared__ ushort As[4*34*64];            // 17408 B
    __shared__ float  w9s[256*10];            // 10240 B
    __shared__ __align__(16) char uB[34816];  // union
    ushort*   Ls16     = (ushort*)uB;                 // 64*130 f16 (ph1-2)
    float*    wk2t     = (float*)(uB + 16640);        // 128*12  (ph2)
    float*    contribs = (float*)(uB + 22784);        // 512     (ph2)
    _Float16* fqs      = (_Float16*)uB;               // 256*68  (ph3-4)

    const int t   = threadIdx.x;
    const int blk = blockIdx.x;
    const int b   = blk >> 8;
    const int rem = blk & 255;
    const int cy0 = (rem >> 2) * 2;
    const int cx0 = (rem & 3) * 32;

    // ---- stage ----
    for (int e = t; e < 1088; e += 512){
        const int r   = e / 272;
        const int rm  = e - r * 272;
        const int col = rm >> 3;
        const int cb  = rm & 7;
        const ushort* src = featTp + ((((size_t)b*130 + cy0 + r)*130 + cx0 + col) << 6) + cb*8;
        const int didx = (r*34 + col)*64 + ((cb ^ (col & 7)) << 3);
        *(int4*)&As[didx] = *(const int4*)src;
    }
    for (int e = t; e < 1536; e += 512){
        const int o = (e * 10923) >> 17;   // e/12
        const int k = e - o*12;
        if (k < 9) wk2t[e] = wk2[k*128 + o];
    }
    contribs[t] = contrib[t & 511];
    __syncthreads();

    // ---- Phase 1: MFMA conv -> Ls16 (f16) ----
    {
        const int lane = t & 63;
        const int w    = t >> 6;
        const int wn   = w & 1;
        const int wq   = w >> 1;
        const int cellrow = wq >> 1;
        const int colblk  = (wq & 1) * 16;
        const int l15  = lane & 15;
        const int l4   = lane >> 4;

        f32x4 acc[4];
        #pragma unroll
        for (int n = 0; n < 4; ++n) acc[n] = (f32x4){0.f,0.f,0.f,0.f};

        const int acol = colblk + l15;

        #pragma unroll
        for (int tap = 0; tap < 9; ++tap){
            const int ky = tap / 3;
            const int kx = tap - ky * 3;

            s16x8 bf[2][4];
            #pragma unroll
            for (int ks = 0; ks < 2; ++ks)
                #pragma unroll
                for (int n = 0; n < 4; ++n)
                    bf[ks][n] = *(const s16x8*)(wk1tap +
                        (((size_t)tap << 13) + ((wn*64 + n*16 + l15) << 6) + ks*32 + l4*8));

            const int col = acol + kx;
            const int rowbase = (cellrow + ky)*34 + col;
            const int sw = (col & 7);
            #pragma unroll
            for (int ks = 0; ks < 2; ++ks){
                const int cb0 = ks*4 + l4;
                const s16x8 af = *(const s16x8*)&As[rowbase*64 + ((cb0 ^ sw) << 3)];
                #pragma unroll
                for (int n = 0; n < 4; ++n)
                    acc[n] = __builtin_amdgcn_mfma_f32_16x16x32_bf16(af, bf[ks][n], acc[n], 0, 0, 0);
            }
        }

        #pragma unroll
        for (int n = 0; n < 4; ++n){
            #pragma unroll
            for (int reg = 0; reg < 4; ++reg){
                const int lc = cellrow*32 + colblk + l4*4 + reg;
                const int o  = wn*64 + n*16 + l15;
                Ls16[lc*130 + o] = __builtin_bit_cast(ushort, (_Float16)acc[n][reg]);
            }
        }
    }
    __syncthreads();

    // ---- Phase 2: w9 = softmax(wk2 . gelu(L + contrib[p]) + bk2) ----
    if (t < 256){
        const int cell = t & 63;     // lane = cell -> 2-way (free) Ls reads
        const int p    = t >> 6;     // wave-uniform

        float w9[9];
        #pragma unroll
        for (int k = 0; k < 9; ++k) w9[k] = 0.0f;

        const float* __restrict__ cp = contribs + p*128;
        for (int o = 0; o < 128; ++o){
            const float lv = (float)__builtin_bit_cast(_Float16, Ls16[cell*130 + o]);
            const float h  = gelu2(lv + cp[o]);
            const f32x4 wa = *(const f32x4*)&wk2t[o*12];
            const f32x4 wb = *(const f32x4*)&wk2t[o*12 + 4];
            w9[0] += h*wa[0]; w9[1] += h*wa[1]; w9[2] += h*wa[2]; w9[3] += h*wa[3];
            w9[4] += h*wb[0]; w9[5] += h*wb[1]; w9[6] += h*wb[2]; w9[7] += h*wb[3];
            w9[8] += h*wk2t[o*12 + 8];
        }
        #pragma unroll
        for (int k = 0; k < 9; ++k) w9[k] += bk2[k];

        float mx = w9[0];
        #pragma unroll
        for (int k = 1; k < 9; ++k) mx = fmaxf(mx, w9[k]);
        float sum = 0.0f;
        #pragma unroll
        for (int k = 0; k < 9; ++k){ w9[k] = __expf(w9[k] - mx); sum += w9[k]; }
        const float inv = __builtin_amdgcn_rcpf(sum);
        #pragma unroll
        for (int k = 0; k < 9; ++k) w9s[t*10 + k] = w9[k] * inv;
    }
    __syncthreads();

    // ---- Phase 3: fq (4 parities, 8 ch) per thread -> fqs LDS (fp16) ----
    // NOTE: fqs overlays Ls16/wk2t/contribs, all dead after phase 2.
    {
        const int ci  = t >> 3;          // cell 0..63
        const int sub = t & 7;           // channel block
        const int rr  = ci >> 5;
        const int x   = ci & 31;
        const int base_rc = rr*34 + x;
        const int c0 = sub*8;

        float w9r[4][9];
        #pragma unroll
        for (int p = 0; p < 4; ++p)
            #pragma unroll
            for (int k = 0; k < 9; ++k)
                w9r[p][k] = w9s[(p*64 + ci)*10 + k];

        float fqa[4][8];
        #pragma unroll
        for (int p = 0; p < 4; ++p)
            #pragma unroll
            for (int i = 0; i < 8; ++i) fqa[p][i] = 0.0f;

        #pragma unroll
        for (int k = 0; k < 9; ++k){
            #pragma unroll
            for (int i = 0; i < 8; ++i){
                const int e   = k*64 + c0 + i;
                const int ch  = (e * 7282) >> 16;     // e/9
                const int tap = e - 9*ch;
                const int ty  = (tap * 11) >> 5;      // tap/3
                const int tx  = tap - 3*ty;
                const int col = x + tx;
                const int aidx = ((base_rc + ty*34 + tx) << 6)
                               + (((ch >> 3) ^ (col & 7)) << 3) + (ch & 7);
                const float v = bf2f(As[aidx]);
                fqa[0][i] += w9r[0][k] * v;
                fqa[1][i] += w9r[1][k] * v;
                fqa[2][i] += w9r[2][k] * v;
                fqa[3][i] += w9r[3][k] * v;
            }
        }

        // pixel index P = p*64 + cell; fqs pitch 68 (2-way-free b128 reads)
        #pragma unroll
        for (int p = 0; p < 4; ++p){
            h16x8 hv;
            #pragma unroll
            for (int i = 0; i < 8; ++i) hv[i] = (_Float16)fqa[p][i];
            *(h16x8*)&fqs[(p*64 + ci)*68 + c0] = hv;
        }
    }
    __syncthreads();

    // ---- Phase 4: RGB MLP via fp16 MFMA (M=256,K=64,N=64) + layer2 + store ----
    {
        const int lane = t & 63;
        const int w    = t >> 6;
        const int l15  = lane & 15;
        const int l4   = lane >> 4;

        f32x4 br1v, wv0, wv1, wv2;
        #pragma unroll
        for (int n = 0; n < 4; ++n){
            const int col = n*16 + l15;
            br1v[n] = br1[col];
            wv0[n]  = wr2[col];
            wv1[n]  = wr2[64 + col];
            wv2[n]  = wr2[128 + col];
        }
        const float b2r0 = br2[0], b2r1 = br2[1], b2r2 = br2[2];

        #pragma unroll
        for (int m2 = 0; m2 < 2; ++m2){
            const int m   = w*2 + m2;        // M-tile 0..15
            const int row = m*16 + l15;      // pixel P = p*64 + cell

            const h16x8 a0 = *(const h16x8*)&fqs[row*68 + l4*8];
            const h16x8 a1 = *(const h16x8*)&fqs[row*68 + 32 + l4*8];

            f32x4 acc[4];
            #pragma unroll
            for (int n = 0; n < 4; ++n){
                const h16x8 b0 = *(const h16x8*)&wr1h[(n*16 + l15)*64 + l4*8];
                const h16x8 b1 = *(const h16x8*)&wr1h[(n*16 + l15)*64 + 32 + l4*8];
                acc[n] = (f32x4){0.f,0.f,0.f,0.f};
                acc[n] = __builtin_amdgcn_mfma_f32_16x16x32_f16(a0, b0, acc[n], 0, 0, 0);
                acc[n] = __builtin_amdgcn_mfma_f32_16x16x32_f16(a1, b1, acc[n], 0, 0, 0);
            }

            #pragma unroll
            for (int reg = 0; reg < 4; ++reg){
                float r0 = 0.f, r1 = 0.f, r2 = 0.f;
                #pragma unroll
                for (int n = 0; n < 4; ++n){
                    const float h = gelu2(acc[n][reg] + br1v[n]);
                    r0 += h * wv0[n];
                    r1 += h * wv1[n];
                    r2 += h * wv2[n];
                }
                r0 += __shfl_xor(r0, 1); r0 += __shfl_xor(r0, 2); r0 += __shfl_xor(r0, 4); r0 += __shfl_xor(r0, 8);
                r1 += __shfl_xor(r1, 1); r1 += __shfl_xor(r1, 2); r1 += __shfl_xor(r1, 4); r1 += __shfl_xor(r1, 8);
                r2 += __shfl_xor(r2, 1); r2 += __shfl_xor(r2, 2); r2 += __shfl_xor(r2, 4); r2 += __shfl_xor(r2, 8);

                if (l15 == 0){
                    const int row2 = m*16 + l4*4 + reg;  // P = p*64 + cell
                    const int p    = row2 >> 6;
                    const int cell = row2 & 63;
                    const int gy = cy0 + (cell >> 5);
                    const int gx = cx0 + (cell & 31);
                    const int py = p >> 1, px = p & 1;

                    const float v0 = r0 + b2r0, v1 = r1 + b2r1, v2 = r2 + b2r2;
                    const int oy0 = 2*gy + 2 - py;
                    const int ox0 = 2*gx + 2 - px;
                    const bool y0ok = (py == 1) || (gy < 127);
                    const bool x0ok = (px == 1) || (gx < 127);
                    const bool yEx  = (gy == 0) && (py == 0);
                    const bool xEx  = (gx == 0) && (px == 0);

                    const size_t ob = ((size_t)b*3) << 16;
                    if (y0ok && x0ok){
                        const int pix = (oy0 << 8) | ox0;
                        out[ob + pix] = v0; out[ob + 65536 + pix] = v1; out[ob + 131072 + pix] = v2;
                    }
                    if (y0ok && xEx){
                        const int pix = (oy0 << 8);
                        out[ob + pix] = v0; out[ob + 65536 + pix] = v1; out[ob + 131072 + pix] = v2;
                    }
                    if (yEx && x0ok){
                        const int pix = ox0;
                        out[ob + pix] = v0; out[ob + 65536 + pix] = v1; out[ob + 131072 + pix] = v2;
                    }
                    if (yEx && xEx){
                        out[ob] = v0; out[ob + 65536] = v1; out[ob + 131072] = v2;
                    }
                }
            }
        }
    }
}

// ---------------------------------------------------------------------------
// Fallback monolithic kernel (round-1 proven; used only if ws too small)
// ---------------------------------------------------------------------------
__global__ __launch_bounds__(256) void main_kernel_mono(
    const float* __restrict__ feat,
    const float* __restrict__ wk1,
    const float* __restrict__ wk2, const float* __restrict__ bk2,
    const float* __restrict__ wr1, const float* __restrict__ br1,
    const float* __restrict__ wr2, const float* __restrict__ br2,
    const float* __restrict__ contrib,
    float* __restrict__ out)
{
    const int tid = blockIdx.x * 256 + threadIdx.x;
    const int b  = tid >> 16;
    const int qi = tid & 65535;
    const int oy = qi >> 8;
    const int ox = qi & 255;

    int cy = (oy - 1) >> 1; if (cy < 0) cy = 0;
    int cx = (ox - 1) >> 1; if (cx < 0) cx = 0;

    int ry[3], rx[3];
    #pragma unroll
    for (int k = 0; k < 3; ++k){ ry[k] = refl(cy-1+k, HH); rx[k] = refl(cx-1+k, WW); }

    const int p = ((oy & 1) << 1) | (ox & 1);
    const float* __restrict__ fb = feat + ((size_t)b << 20);

    float w9[9];
    #pragma unroll
    for (int k = 0; k < 9; ++k) w9[k] = bk2[k];

    for (int oc = 0; oc < 4; ++oc){
        float acc[32];
        #pragma unroll
        for (int j = 0; j < 32; ++j) acc[j] = contrib[p*128 + oc*32 + j];
        for (int c = 0; c < 64; ++c){
            const float* __restrict__ fc = fb + c * (HH*WW);
            float v[9];
            #pragma unroll
            for (int ky = 0; ky < 3; ++ky){
                const float* __restrict__ frow = fc + ry[ky] * WW;
                #pragma unroll
                for (int kx = 0; kx < 3; ++kx) v[ky*3 + kx] = frow[rx[kx]];
            }
            const float* __restrict__ wrow0 = wk1 + (oc*32) * 640 + c * 9;
            #pragma unroll
            for (int j = 0; j < 32; ++j){
                const float* __restrict__ wrow = wrow0 + j * 640;
                float a = acc[j];
                #pragma unroll
                for (int kk = 0; kk < 9; ++kk) a += v[kk] * wrow[kk];
                acc[j] = a;
            }
        }
        #pragma unroll
        for (int j = 0; j < 32; ++j){
            const float h = gelu_f(acc[j]);
            const int o = oc*32 + j;
            #pragma unroll
            for (int k = 0; k < 9; ++k) w9[k] += h * wk2[k*128 + o];
        }
    }

    float mx = w9[0];
    #pragma unroll
    for (int k = 1; k < 9; ++k) mx = fmaxf(mx, w9[k]);
    float sum = 0.0f;
    #pragma unroll
    for (int k = 0; k < 9; ++k){ w9[k] = expf(w9[k] - mx); sum += w9[k]; }
    const float inv = 1.0f / sum;
    #pragma unroll
    for (int k = 0; k < 9; ++k) w9[k] *= inv;

    float fq[64];
    #pragma unroll
    for (int c = 0; c < 64; ++c){
        float a = 0.0f;
        #pragma unroll
        for (int k = 0; k < 9; ++k){
            const int j  = k*64 + c;
            const int ch = j / 9;
            const int kk = j % 9;
            a += w9[k] * fb[ch*(HH*WW) + ry[kk/3]*WW + rx[kk%3]];
        }
        fq[c] = a;
    }

    float r0 = br2[0], r1 = br2[1], r2 = br2[2];
    for (int o = 0; o < 64; ++o){
        float a = br1[o];
        #pragma unroll
        for (int c = 0; c < 64; ++c) a += fq[c] * wr1[o*64 + c];
        const float h = gelu_f(a);
        r0 += h * wr2[o];
        r1 += h * wr2[64 + o];
        r2 += h * wr2[128 + o];
    }

    const int pix = (oy << 8) | ox;
    out[((size_t)(b*3 + 0) << 16) + pix] = r0;
    out[((size_t)(b*3 + 1) << 16) + pix] = r1;
    out[((size_t)(b*3 + 2) << 16) + pix] = r2;
}

extern "C" void kernel_launch(void* const* d_in, const int* in_sizes, int n_in,
                              void* d_out, int out_size, void* d_ws, size_t ws_size,
                              hipStream_t stream)
{
    const float* feat = (const float*)d_in[0];
    const float* w1m  = (const float*)d_in[1];
    const float* b1m  = (const float*)d_in[2];
    const float* w2m  = (const float*)d_in[3];
    const float* b2m  = (const float*)d_in[4];
    const float* wk1  = (const float*)d_in[5];
    const float* bk1  = (const float*)d_in[6];
    const float* wk2  = (const float*)d_in[7];
    const float* bk2  = (const float*)d_in[8];
    const float* wr1  = (const float*)d_in[9];
    const float* br1  = (const float*)d_in[10];
    const float* wr2  = (const float*)d_in[11];
    const float* br2  = (const float*)d_in[12];

    float* out = (float*)d_out;

    // ws layout (~4.5 MB):
    char* ws = (char*)d_ws;
    float*     contrib = (float*)ws;                       //       0 .. 2048
    ushort*    wk1tap  = (ushort*)(ws + 8192);             //    8192 .. 155648
    _Float16*  wr1h    = (_Float16*)(ws + 155648);         //  155648 .. 172032
    ushort*    featTp  = (ushort*)(ws + 172032);           //  172032 .. 4498432
    const size_t need = 4498432;

    if (ws_size >= need){
        hipLaunchKernelGGL(prep_all, dim3(581), dim3(256), 0, stream,
                           w1m, b1m, w2m, b2m, wk1, bk1, wr1, feat,
                           contrib, wk1tap, wr1h, featTp);
        hipLaunchKernelGGL(conv_fused, dim3(512), dim3(512), 0, stream,
                           featTp, wk1tap, wk2, bk2, contrib,
                           wr1h, br1, wr2, br2, out);
    } else {
        hipLaunchKernelGGL(prep_all, dim3(321), dim3(256), 0, stream,
                           w1m, b1m, w2m, b2m, wk1, bk1, wr1, feat,
                           contrib, wk1tap, wr1h, featTp);
        hipLaunchKernelGGL(main_kernel_mono, dim3(512), dim3(256), 0, stream,
                           feat, wk1, wk2, bk2, wr1, br1, wr2, br2, contrib, out);
    }
}